// Round 1
// baseline (1543.310 us; speedup 1.0000x reference)
//
#include <hip/hip_runtime.h>
#include <math.h>

#define NIMG 8
#define TT   159882
#define KTOT 4507
#define POST 1000

__constant__ int c_n[5]   = {120000,30000,7500,1875,507};
__constant__ int c_off[5] = {0,120000,150000,157500,159375};
__constant__ int c_k[5]   = {1000,1000,1000,1000,507};
__constant__ int c_pos[5] = {0,1000,2000,3000,4000};

__device__ __forceinline__ unsigned fkey(float f){
  unsigned u=__float_as_uint(f);
  return (u&0x80000000u)? ~u : (u|0x80000000u);
}

// ---------------- K1: per-(img,level) exact top-k by logit, then sort level list
// by (logit desc, idx asc) to reconstruct reference gather order ----------------
__global__ __launch_bounds__(256) void k_topk(const float* __restrict__ obj,
                                              int* __restrict__ sel,
                                              int* __restrict__ eqbuf){
  const int img=blockIdx.x/5, lvl=blockIdx.x%5;
  const float* o = obj + (size_t)img*TT + c_off[lvl];
  const int n=c_n[lvl], k=c_k[lvl];
  __shared__ unsigned hist[2048];
  __shared__ unsigned s_prefix; __shared__ int s_krem;
  __shared__ int s_gt, s_eq;
  __shared__ unsigned long long skey[1024];

  unsigned t=0; int krem=0;
  if(k<n){
    unsigned prefix=0; int kr=k;
    const int sh[3]={21,10,0}; const int wd[3]={11,11,10};
    for(int r=0;r<3;r++){
      const int nb=1<<wd[r];
      for(int i=threadIdx.x;i<nb;i+=256) hist[i]=0u;
      __syncthreads();
      unsigned hiMask=(r==0)?0u:(0xFFFFFFFFu<<sh[r-1]);
      for(int i=threadIdx.x;i<n;i+=256){
        unsigned key=fkey(o[i]);
        if(r==0 || (key&hiMask)==prefix){
          atomicAdd(&hist[(key>>sh[r])&(unsigned)(nb-1)],1u);
        }
      }
      __syncthreads();
      if(threadIdx.x==0){
        unsigned cum=0; int bs=0;
        for(int b=nb-1;b>=0;b--){
          if(cum+hist[b]>=(unsigned)kr){ bs=b; break; }
          cum+=hist[b];
        }
        s_prefix=prefix|((unsigned)bs<<sh[r]);
        s_krem=kr-(int)cum;
      }
      __syncthreads();
      prefix=s_prefix; kr=s_krem;
      __syncthreads();
    }
    t=prefix; krem=kr;
  }
  if(threadIdx.x==0){ s_gt=0; s_eq=0; }
  __syncthreads();
  int* eq = eqbuf + blockIdx.x*2048;
  int* s  = sel + img*KTOT + c_pos[lvl];
  for(int i=threadIdx.x;i<n;i+=256){
    unsigned key=fkey(o[i]);
    if(key>t){ s[atomicAdd(&s_gt,1)]=i; }
    else if(key==t && krem>0){ int p=atomicAdd(&s_eq,1); if(p<2048) eq[p]=i; }
  }
  __syncthreads();
  if(threadIdx.x==0){
    int cgt=s_gt, ceq=min(s_eq,2048);
    for(int r2=0;r2<krem;r2++){
      int mn=0x7fffffff, mi=0;
      for(int j=0;j<ceq;j++) if(eq[j]<mn){ mn=eq[j]; mi=j; }
      s[cgt+r2]=mn; eq[mi]=0x7fffffff;
    }
  }
  __syncthreads();
  // sort level list: (logit desc, idx asc) -- rank sort, keys unique via idx
  for(int i=threadIdx.x;i<k;i+=256){
    int idx=s[i];
    skey[i]=((unsigned long long)fkey(o[idx])<<32)|(unsigned)(~(unsigned)idx);
  }
  __syncthreads();
  for(int i=threadIdx.x;i<k;i+=256){
    unsigned long long mk=skey[i];
    int rank=0;
    for(int j=0;j<k;j++) rank += (skey[j]>mk)?1:0;
    int idx=(int)(~(unsigned)(mk&0xFFFFFFFFu));
    s[rank]=idx+c_off[lvl];   // store global anchor index at its gather position
  }
}

// ---------------- K2a: decode+clip+score, build global sort keys, image max ----
__global__ __launch_bounds__(256) void k_decode(const float* __restrict__ obj,
    const float* __restrict__ del, const float* __restrict__ anc,
    const int* __restrict__ sel, float* __restrict__ pbox, float* __restrict__ pscore,
    int* __restrict__ plvl, unsigned long long* __restrict__ gkey,
    float* __restrict__ gmax){
  const int img=blockIdx.x;
  __shared__ float smax[256];
  const float BCLIP=(float)4.135166556742356;  // log(1000/16)
  float lm=0.f;
  for(int pos=threadIdx.x;pos<KTOT;pos+=256){
    int lvl = pos<1000?0:pos<2000?1:pos<3000?2:pos<4000?3:4;
    int tdx = sel[img*KTOT+pos];
    float logit = obj[(size_t)img*TT+tdx];
    const float* a=anc+4*(size_t)tdx;
    const float* d=del+((size_t)img*TT+tdx)*4;
    float w=a[2]-a[0], h=a[3]-a[1];
    float cx=a[0]+0.5f*w, cy=a[1]+0.5f*h;
    float dw=fminf(d[2],BCLIP), dh=fminf(d[3],BCLIP);
    float pcx=d[0]*w+cx, pcy=d[1]*h+cy;
    float pw=expf(dw)*w, ph=expf(dh)*h;
    float x1=pcx-0.5f*pw, y1=pcy-0.5f*ph;
    float x2=pcx+0.5f*pw, y2=pcy+0.5f*ph;
    x1=fminf(fmaxf(x1,0.f),800.f); y1=fminf(fmaxf(y1,0.f),800.f);
    x2=fminf(fmaxf(x2,0.f),800.f); y2=fminf(fmaxf(y2,0.f),800.f);
    int valid=(x2-x1>=1e-3f)&&(y2-y1>=1e-3f);
    float sc=1.f/(1.f+expf(-logit));
    float sv=valid? sc : -INFINITY;
    // key: score desc, then position asc (stable argsort replication)
    gkey[img*KTOT+pos]=((unsigned long long)fkey(sv)<<32)|(unsigned)(KTOT-1-pos);
    float* pb=pbox+((size_t)img*KTOT+pos)*4;
    pb[0]=x1; pb[1]=y1; pb[2]=x2; pb[3]=y2;
    pscore[img*KTOT+pos]=sc;
    plvl[img*KTOT+pos]=lvl|(valid?0:256);
    lm=fmaxf(lm,fmaxf(fmaxf(x1,y1),fmaxf(x2,y2)));
  }
  smax[threadIdx.x]=lm; __syncthreads();
  for(int st=128;st>0;st>>=1){
    if(threadIdx.x<st) smax[threadIdx.x]=fmaxf(smax[threadIdx.x],smax[threadIdx.x+st]);
    __syncthreads();
  }
  if(threadIdx.x==0) gmax[img]=smax[0];
}

// ---------------- K2b: global rank sort (score desc, pos asc) + scatter -------
__global__ __launch_bounds__(256) void k_rank(const unsigned long long* __restrict__ gkey,
    const float* __restrict__ pbox, const float* __restrict__ pscore,
    const int* __restrict__ plvl,
    float* __restrict__ sbox, float* __restrict__ sscore,
    int* __restrict__ slvl, int* __restrict__ ssupp){
  const int img=blockIdx.x/18, chunk=blockIdx.x%18;
  __shared__ unsigned long long key[KTOT];
  for(int i=threadIdx.x;i<KTOT;i+=256) key[i]=gkey[img*KTOT+i];
  __syncthreads();
  int pos=chunk*256+threadIdx.x;
  if(pos<KTOT){
    unsigned long long mk=key[pos];
    int rank=0;
    for(int j=0;j<KTOT;j++) rank+=(key[j]>mk)?1:0;
    const float* pb=pbox+((size_t)img*KTOT+pos)*4;
    float* sb=sbox+((size_t)img*KTOT+rank)*4;
    sb[0]=pb[0]; sb[1]=pb[1]; sb[2]=pb[2]; sb[3]=pb[3];
    sscore[img*KTOT+rank]=pscore[img*KTOT+pos];
    int lv=plvl[img*KTOT+pos];
    slvl[img*KTOT+rank]=lv&0xFF;
    ssupp[img*KTOT+rank]=(lv>>8)&1;   // invalid -> pre-suppressed
  }
}

// ---------------- K3: greedy NMS per (img,level) over sorted order ------------
__global__ __launch_bounds__(256) void k_nms(const float* __restrict__ sbox,
    const int* __restrict__ slvl, int* __restrict__ ssupp,
    const float* __restrict__ gmax){
  const int img=blockIdx.x/5, lvl=blockIdx.x%5;
  __shared__ unsigned short list[1000];
  __shared__ float bx0[1000], by0[1000], bx1[1000], by1[1000], area[1000];
  __shared__ unsigned char sup[1000];
  __shared__ int s_m;
  if(threadIdx.x==0){
    int m=0;
    for(int r=0;r<KTOT;r++){
      int base=img*KTOT+r;
      if(slvl[base]==lvl && !ssupp[base]){ list[m++]=(unsigned short)r; }
    }
    s_m=m;
  }
  __syncthreads();
  const int m=s_m;
  const float off=(float)lvl*(gmax[img]+1.0f);   // replicate ref offset math exactly
  for(int i=threadIdx.x;i<m;i+=256){
    int r=list[i];
    const float* b=sbox+((size_t)img*KTOT+r)*4;
    float a0=b[0]+off, a1=b[1]+off, a2=b[2]+off, a3=b[3]+off;
    bx0[i]=a0; by0[i]=a1; bx1[i]=a2; by1[i]=a3;
    area[i]=(a2-a0)*(a3-a1);
    sup[i]=0;
  }
  __syncthreads();
  for(int i=0;i<m;i++){
    if(!sup[i]){
      float a0=bx0[i],a1=by0[i],a2=bx1[i],a3=by1[i],aa=area[i];
      for(int j=i+1+threadIdx.x;j<m;j+=256){
        if(!sup[j]){
          float ltx=fmaxf(a0,bx0[j]), lty=fmaxf(a1,by0[j]);
          float rbx=fminf(a2,bx1[j]), rby=fminf(a3,by1[j]);
          float wx=fmaxf(rbx-ltx,0.f), wy=fmaxf(rby-lty,0.f);
          float inter=wx*wy;
          float iou=inter/((aa+area[j])-inter);
          if(iou>0.7f) sup[j]=1;
        }
      }
    }
    __syncthreads();
  }
  for(int i=threadIdx.x;i<m;i+=256) if(sup[i]) ssupp[img*KTOT+list[i]]=1;
}

// ---------------- K4: compact first 1000 survivors per image ------------------
__global__ __launch_bounds__(256) void k_out(const float* __restrict__ sbox,
    const float* __restrict__ sscore, const int* __restrict__ ssupp,
    float* __restrict__ out){
  const int img=blockIdx.x;
  __shared__ unsigned short list[POST];
  __shared__ int s_c;
  if(threadIdx.x==0){
    int c=0;
    for(int r=0;r<KTOT && c<POST;r++) if(!ssupp[img*KTOT+r]) list[c++]=(unsigned short)r;
    s_c=c;
  }
  __syncthreads();
  const int c=s_c;
  for(int o=threadIdx.x;o<POST;o+=256){
    float* row=out+((size_t)img*POST+o)*5;
    if(o<c){
      int r=list[o];
      const float* b=sbox+((size_t)img*KTOT+r)*4;
      row[0]=b[0]; row[1]=b[1]; row[2]=b[2]; row[3]=b[3];
      row[4]=sscore[img*KTOT+r];
    } else {
      row[0]=0.f; row[1]=0.f; row[2]=0.f; row[3]=0.f; row[4]=0.f;
    }
  }
}

extern "C" void kernel_launch(void* const* d_in, const int* in_sizes, int n_in,
                              void* d_out, int out_size, void* d_ws, size_t ws_size,
                              hipStream_t stream){
  const float* obj=(const float*)d_in[0];
  const float* del=(const float*)d_in[1];
  const float* anc=(const float*)d_in[2];
  float* out=(float*)d_out;

  char* w=(char*)d_ws;
  size_t off=0;
  auto alloc=[&](size_t bytes)->void*{
    void* p=w+off; off+=(bytes+255)&~(size_t)255; return p;
  };
  int*  sel    =(int*)  alloc(sizeof(int)*NIMG*KTOT);
  float* pbox  =(float*)alloc(sizeof(float)*NIMG*KTOT*4);
  float* pscore=(float*)alloc(sizeof(float)*NIMG*KTOT);
  int*  plvl   =(int*)  alloc(sizeof(int)*NIMG*KTOT);
  unsigned long long* gkey=(unsigned long long*)alloc(sizeof(unsigned long long)*NIMG*KTOT);
  float* sbox  =(float*)alloc(sizeof(float)*NIMG*KTOT*4);
  float* sscore=(float*)alloc(sizeof(float)*NIMG*KTOT);
  int*  slvl   =(int*)  alloc(sizeof(int)*NIMG*KTOT);
  int*  ssupp  =(int*)  alloc(sizeof(int)*NIMG*KTOT);
  float* gmax  =(float*)alloc(sizeof(float)*NIMG);
  int*  eqbuf  =(int*)  alloc(sizeof(int)*40*2048);

  hipLaunchKernelGGL(k_topk,   dim3(40), dim3(256), 0, stream, obj, sel, eqbuf);
  hipLaunchKernelGGL(k_decode, dim3(NIMG), dim3(256), 0, stream, obj, del, anc, sel,
                     pbox, pscore, plvl, gkey, gmax);
  hipLaunchKernelGGL(k_rank,   dim3(NIMG*18), dim3(256), 0, stream, gkey, pbox, pscore,
                     plvl, sbox, sscore, slvl, ssupp);
  hipLaunchKernelGGL(k_nms,    dim3(40), dim3(256), 0, stream, sbox, slvl, ssupp, gmax);
  hipLaunchKernelGGL(k_out,    dim3(NIMG), dim3(256), 0, stream, sbox, sscore, ssupp, out);
}

// Round 2
// 826.987 us; speedup vs baseline: 1.8662x; 1.8662x over previous
//
#include <hip/hip_runtime.h>
#include <math.h>

#define NIMG 8
#define TT   159882
#define KTOT 4507
#define POST 1000

__constant__ int c_n[5]   = {120000,30000,7500,1875,507};
__constant__ int c_off[5] = {0,120000,150000,157500,159375};
__constant__ int c_k[5]   = {1000,1000,1000,1000,507};
__constant__ int c_pos[5] = {0,1000,2000,3000,4000};

__device__ __forceinline__ unsigned fkey(float f){
  unsigned u=__float_as_uint(f);
  return (u&0x80000000u)? ~u : (u|0x80000000u);
}

// ---------------- K1: per-(img,level) exact top-k by logit, then sort level list
// by (logit desc, idx asc) to reconstruct reference gather order ----------------
__global__ __launch_bounds__(256) void k_topk(const float* __restrict__ obj,
                                              int* __restrict__ sel,
                                              int* __restrict__ eqbuf){
  const int img=blockIdx.x/5, lvl=blockIdx.x%5;
  const float* o = obj + (size_t)img*TT + c_off[lvl];
  const int n=c_n[lvl], k=c_k[lvl];
  __shared__ unsigned hist[2048];
  __shared__ unsigned s_prefix; __shared__ int s_krem;
  __shared__ int s_gt, s_eq;
  __shared__ unsigned long long skey[1024];

  unsigned t=0; int krem=0;
  if(k<n){
    unsigned prefix=0; int kr=k;
    const int sh[3]={21,10,0}; const int wd[3]={11,11,10};
    for(int r=0;r<3;r++){
      const int nb=1<<wd[r];
      for(int i=threadIdx.x;i<nb;i+=256) hist[i]=0u;
      __syncthreads();
      unsigned hiMask=(r==0)?0u:(0xFFFFFFFFu<<sh[r-1]);
      for(int i=threadIdx.x;i<n;i+=256){
        unsigned key=fkey(o[i]);
        if(r==0 || (key&hiMask)==prefix){
          atomicAdd(&hist[(key>>sh[r])&(unsigned)(nb-1)],1u);
        }
      }
      __syncthreads();
      if(threadIdx.x==0){
        unsigned cum=0; int bs=0;
        for(int b=nb-1;b>=0;b--){
          if(cum+hist[b]>=(unsigned)kr){ bs=b; break; }
          cum+=hist[b];
        }
        s_prefix=prefix|((unsigned)bs<<sh[r]);
        s_krem=kr-(int)cum;
      }
      __syncthreads();
      prefix=s_prefix; kr=s_krem;
      __syncthreads();
    }
    t=prefix; krem=kr;
  }
  if(threadIdx.x==0){ s_gt=0; s_eq=0; }
  __syncthreads();
  int* eq = eqbuf + blockIdx.x*2048;
  int* s  = sel + img*KTOT + c_pos[lvl];
  for(int i=threadIdx.x;i<n;i+=256){
    unsigned key=fkey(o[i]);
    if(key>t){ s[atomicAdd(&s_gt,1)]=i; }
    else if(key==t && krem>0){ int p=atomicAdd(&s_eq,1); if(p<2048) eq[p]=i; }
  }
  __syncthreads();
  if(threadIdx.x==0){
    int cgt=s_gt, ceq=min(s_eq,2048);
    for(int r2=0;r2<krem;r2++){
      int mn=0x7fffffff, mi=0;
      for(int j=0;j<ceq;j++) if(eq[j]<mn){ mn=eq[j]; mi=j; }
      s[cgt+r2]=mn; eq[mi]=0x7fffffff;
    }
  }
  __syncthreads();
  // sort level list: (logit desc, idx asc) -- rank sort, keys unique via idx
  for(int i=threadIdx.x;i<k;i+=256){
    int idx=s[i];
    skey[i]=((unsigned long long)fkey(o[idx])<<32)|(unsigned)(~(unsigned)idx);
  }
  __syncthreads();
  for(int i=threadIdx.x;i<k;i+=256){
    unsigned long long mk=skey[i];
    int rank=0;
    for(int j=0;j<k;j++) rank += (skey[j]>mk)?1:0;
    int idx=(int)(~(unsigned)(mk&0xFFFFFFFFu));
    s[rank]=idx+c_off[lvl];   // store global anchor index at its gather position
  }
}

// ---------------- K2a: decode+clip+score, build global sort keys, image max ----
__global__ __launch_bounds__(256) void k_decode(const float* __restrict__ obj,
    const float* __restrict__ del, const float* __restrict__ anc,
    const int* __restrict__ sel, float* __restrict__ pbox, float* __restrict__ pscore,
    int* __restrict__ plvl, unsigned long long* __restrict__ gkey,
    float* __restrict__ gmax){
  const int img=blockIdx.x;
  __shared__ float smax[256];
  const float BCLIP=(float)4.135166556742356;  // log(1000/16)
  float lm=0.f;
  for(int pos=threadIdx.x;pos<KTOT;pos+=256){
    int lvl = pos<1000?0:pos<2000?1:pos<3000?2:pos<4000?3:4;
    int tdx = sel[img*KTOT+pos];
    float logit = obj[(size_t)img*TT+tdx];
    const float* a=anc+4*(size_t)tdx;
    const float* d=del+((size_t)img*TT+tdx)*4;
    float w=a[2]-a[0], h=a[3]-a[1];
    float cx=a[0]+0.5f*w, cy=a[1]+0.5f*h;
    float dw=fminf(d[2],BCLIP), dh=fminf(d[3],BCLIP);
    float pcx=d[0]*w+cx, pcy=d[1]*h+cy;
    float pw=expf(dw)*w, ph=expf(dh)*h;
    float x1=pcx-0.5f*pw, y1=pcy-0.5f*ph;
    float x2=pcx+0.5f*pw, y2=pcy+0.5f*ph;
    x1=fminf(fmaxf(x1,0.f),800.f); y1=fminf(fmaxf(y1,0.f),800.f);
    x2=fminf(fmaxf(x2,0.f),800.f); y2=fminf(fmaxf(y2,0.f),800.f);
    int valid=(x2-x1>=1e-3f)&&(y2-y1>=1e-3f);
    float sc=1.f/(1.f+expf(-logit));
    float sv=valid? sc : -INFINITY;
    // key: score desc, then position asc (stable argsort replication)
    gkey[img*KTOT+pos]=((unsigned long long)fkey(sv)<<32)|(unsigned)(KTOT-1-pos);
    float* pb=pbox+((size_t)img*KTOT+pos)*4;
    pb[0]=x1; pb[1]=y1; pb[2]=x2; pb[3]=y2;
    pscore[img*KTOT+pos]=sc;
    plvl[img*KTOT+pos]=lvl|(valid?0:256);
    lm=fmaxf(lm,fmaxf(fmaxf(x1,y1),fmaxf(x2,y2)));
  }
  smax[threadIdx.x]=lm; __syncthreads();
  for(int st=128;st>0;st>>=1){
    if(threadIdx.x<st) smax[threadIdx.x]=fmaxf(smax[threadIdx.x],smax[threadIdx.x+st]);
    __syncthreads();
  }
  if(threadIdx.x==0) gmax[img]=smax[0];
}

// ---------------- K2b: global rank sort (score desc, pos asc) + scatter -------
__global__ __launch_bounds__(256) void k_rank(const unsigned long long* __restrict__ gkey,
    const float* __restrict__ pbox, const float* __restrict__ pscore,
    const int* __restrict__ plvl,
    float* __restrict__ sbox, float* __restrict__ sscore,
    int* __restrict__ slvl, int* __restrict__ ssupp){
  const int img=blockIdx.x/18, chunk=blockIdx.x%18;
  __shared__ unsigned long long key[KTOT];
  for(int i=threadIdx.x;i<KTOT;i+=256) key[i]=gkey[img*KTOT+i];
  __syncthreads();
  int pos=chunk*256+threadIdx.x;
  if(pos<KTOT){
    unsigned long long mk=key[pos];
    int rank=0;
    for(int j=0;j<KTOT;j++) rank+=(key[j]>mk)?1:0;
    const float* pb=pbox+((size_t)img*KTOT+pos)*4;
    float* sb=sbox+((size_t)img*KTOT+rank)*4;
    sb[0]=pb[0]; sb[1]=pb[1]; sb[2]=pb[2]; sb[3]=pb[3];
    sscore[img*KTOT+rank]=pscore[img*KTOT+pos];
    int lv=plvl[img*KTOT+pos];
    slvl[img*KTOT+rank]=lv&0xFF;
    ssupp[img*KTOT+rank]=(lv>>8)&1;   // invalid -> pre-suppressed
  }
}

// ---------------- K3a: per-(img,level) ordered candidate list (wave ballot) ---
__global__ __launch_bounds__(64) void k_list(const float* __restrict__ sbox,
    const int* __restrict__ slvl, const int* __restrict__ ssupp,
    const float* __restrict__ gmax,
    int* __restrict__ lists, int* __restrict__ mcnt,
    float4* __restrict__ nbox, float* __restrict__ narea){
  const int img=blockIdx.x/5, lvl=blockIdx.x%5;
  const int lane=threadIdx.x;
  int* list = lists + blockIdx.x*1024;
  int base=0;
  for(int t=0;t<KTOT;t+=64){
    int r=t+lane;
    bool pred = (r<KTOT) && (slvl[img*KTOT+r]==lvl) && (ssupp[img*KTOT+r]==0);
    unsigned long long b=__ballot(pred);
    int prefix=__popcll(b & ((1ull<<lane)-1ull));
    if(pred) list[base+prefix]=r;
    base+=__popcll(b);
  }
  if(lane==0) mcnt[blockIdx.x]=base;
  const int m=base;
  const float off=(float)lvl*(gmax[img]+1.0f);   // replicate ref offset math exactly
  for(int i=lane;i<m;i+=64){
    int r=list[i];
    const float* bx=sbox+((size_t)img*KTOT+r)*4;
    float a0=bx[0]+off, a1=bx[1]+off, a2=bx[2]+off, a3=bx[3]+off;
    nbox[blockIdx.x*1024+i]=make_float4(a0,a1,a2,a3);
    narea[blockIdx.x*1024+i]=(a2-a0)*(a3-a1);
  }
}

// ---------------- K3b: parallel pairwise suppression bitmasks -----------------
__global__ __launch_bounds__(256) void k_mask(const float4* __restrict__ nbox,
    const float* __restrict__ narea, const int* __restrict__ mcnt,
    unsigned long long* __restrict__ mask){
  const int il=blockIdx.x, chunk=blockIdx.y;
  const int m=mcnt[il];
  if(chunk*256>=m) return;
  __shared__ float4 sb[1024];
  __shared__ float  sa[1024];
  for(int i=threadIdx.x;i<m;i+=256){ sb[i]=nbox[il*1024+i]; sa[i]=narea[il*1024+i]; }
  __syncthreads();
  const int i=chunk*256+threadIdx.x;
  if(i>=m) return;
  const float4 bi=sb[i]; const float ai=sa[i];
  const int wlast=(m+63)>>6;
  const int wi=i>>6;             // uniform within each wave (64 consecutive i)
  unsigned long long* out = mask + ((size_t)il*1024 + i)*16;
  for(int w=0;w<16;++w){
    unsigned long long bits=0ull;
    if(w>=wi && w<wlast){
      const int jend=min(64, m-w*64);
      for(int jj=0;jj<jend;++jj){
        const float4 bj=sb[w*64+jj];           // LDS broadcast
        float ltx=fmaxf(bi.x,bj.x), lty=fmaxf(bi.y,bj.y);
        float rbx=fminf(bi.z,bj.z), rby=fminf(bi.w,bj.w);
        float wx=fmaxf(rbx-ltx,0.f), wy=fmaxf(rby-lty,0.f);
        float inter=wx*wy;
        float iou=inter/((ai+sa[w*64+jj])-inter);
        bits |= (iou>0.7f)? (1ull<<jj) : 0ull;
      }
      if(w==wi){ int b=i&63; bits &= ~((2ull<<b)-1ull); }  // keep only j>i
    }
    out[w]=bits;
  }
}

// ---------------- K3c: serial greedy reduce over bitmasks (1 wave/blk) --------
__global__ __launch_bounds__(64) void k_reduce(const unsigned long long* __restrict__ mask,
    const int* __restrict__ mcnt, const int* __restrict__ lists,
    int* __restrict__ ssupp){
  const int il=blockIdx.x, img=il/5;
  const int m=mcnt[il];
  const int lane=threadIdx.x;
  const unsigned long long* M = mask + (size_t)il*1024*16;
  const bool ld = lane<16;
  unsigned long long remv=0ull;
  unsigned long long c0,c1,c2,c3,c4,c5,c6,c7;
  unsigned long long n0,n1,n2,n3,n4,n5,n6,n7;
#define LD(r,b) ((ld && ((b)+(r))<m) ? M[(size_t)((b)+(r))*16+lane] : 0ull)
  c0=LD(0,0); c1=LD(1,0); c2=LD(2,0); c3=LD(3,0);
  c4=LD(4,0); c5=LD(5,0); c6=LD(6,0); c7=LD(7,0);
  for(int g=0;;++g){
    const int nb=(g+1)*8;
    n0=LD(0,nb); n1=LD(1,nb); n2=LD(2,nb); n3=LD(3,nb);
    n4=LD(4,nb); n5=LD(5,nb); n6=LD(6,nb); n7=LD(7,nb);
#define STEP(r,cr) { int i=g*8+(r); if(i<m){ \
    unsigned long long word=__shfl(remv, i>>6); \
    if(((word>>(i&63))&1ull)==0ull) remv|=cr; } }
    STEP(0,c0) STEP(1,c1) STEP(2,c2) STEP(3,c3)
    STEP(4,c4) STEP(5,c5) STEP(6,c6) STEP(7,c7)
#undef STEP
    if(nb>=m) break;
    c0=n0; c1=n1; c2=n2; c3=n3; c4=n4; c5=n5; c6=n6; c7=n7;
  }
#undef LD
  const int* list = lists + il*1024;
  for(int t=0;t<m;t+=64){
    int i=t+lane;
    unsigned long long word=__shfl(remv, (i<m? i:0)>>6);
    if(i<m && ((word>>(i&63))&1ull)) ssupp[img*KTOT+list[i]]=1;
  }
}

// ---------------- K4: compact first 1000 survivors per image ------------------
__global__ __launch_bounds__(256) void k_out(const float* __restrict__ sbox,
    const float* __restrict__ sscore, const int* __restrict__ ssupp,
    float* __restrict__ out){
  const int img=blockIdx.x;
  __shared__ unsigned short list[POST];
  __shared__ int s_c;
  if(threadIdx.x<64){
    int base=0;
    for(int t=0;t<KTOT && base<POST;t+=64){
      int r=t+threadIdx.x;
      bool pred = (r<KTOT) && (ssupp[img*KTOT+r]==0);
      unsigned long long b=__ballot(pred);
      int pre=__popcll(b & ((1ull<<threadIdx.x)-1ull));
      if(pred && base+pre<POST) list[base+pre]=(unsigned short)r;
      base+=__popcll(b);
    }
    if(threadIdx.x==0) s_c=min(base,POST);
  }
  __syncthreads();
  const int c=s_c;
  for(int o=threadIdx.x;o<POST;o+=256){
    float* row=out+((size_t)img*POST+o)*5;
    if(o<c){
      int r=list[o];
      const float* b=sbox+((size_t)img*KTOT+r)*4;
      row[0]=b[0]; row[1]=b[1]; row[2]=b[2]; row[3]=b[3];
      row[4]=sscore[img*KTOT+r];
    } else {
      row[0]=0.f; row[1]=0.f; row[2]=0.f; row[3]=0.f; row[4]=0.f;
    }
  }
}

extern "C" void kernel_launch(void* const* d_in, const int* in_sizes, int n_in,
                              void* d_out, int out_size, void* d_ws, size_t ws_size,
                              hipStream_t stream){
  const float* obj=(const float*)d_in[0];
  const float* del=(const float*)d_in[1];
  const float* anc=(const float*)d_in[2];
  float* out=(float*)d_out;

  char* w=(char*)d_ws;
  size_t off=0;
  auto alloc=[&](size_t bytes)->void*{
    void* p=w+off; off+=(bytes+255)&~(size_t)255; return p;
  };
  int*  sel    =(int*)  alloc(sizeof(int)*NIMG*KTOT);
  float* pbox  =(float*)alloc(sizeof(float)*NIMG*KTOT*4);
  float* pscore=(float*)alloc(sizeof(float)*NIMG*KTOT);
  int*  plvl   =(int*)  alloc(sizeof(int)*NIMG*KTOT);
  unsigned long long* gkey=(unsigned long long*)alloc(sizeof(unsigned long long)*NIMG*KTOT);
  float* sbox  =(float*)alloc(sizeof(float)*NIMG*KTOT*4);
  float* sscore=(float*)alloc(sizeof(float)*NIMG*KTOT);
  int*  slvl   =(int*)  alloc(sizeof(int)*NIMG*KTOT);
  int*  ssupp  =(int*)  alloc(sizeof(int)*NIMG*KTOT);
  float* gmax  =(float*)alloc(sizeof(float)*NIMG);
  int*  eqbuf  =(int*)  alloc(sizeof(int)*40*2048);
  int*  lists  =(int*)  alloc(sizeof(int)*40*1024);
  int*  mcnt   =(int*)  alloc(sizeof(int)*40);
  float4* nbox =(float4*)alloc(sizeof(float4)*40*1024);
  float* narea =(float*)alloc(sizeof(float)*40*1024);
  unsigned long long* mask=(unsigned long long*)alloc(sizeof(unsigned long long)*40*1024*16);

  hipLaunchKernelGGL(k_topk,   dim3(40), dim3(256), 0, stream, obj, sel, eqbuf);
  hipLaunchKernelGGL(k_decode, dim3(NIMG), dim3(256), 0, stream, obj, del, anc, sel,
                     pbox, pscore, plvl, gkey, gmax);
  hipLaunchKernelGGL(k_rank,   dim3(NIMG*18), dim3(256), 0, stream, gkey, pbox, pscore,
                     plvl, sbox, sscore, slvl, ssupp);
  hipLaunchKernelGGL(k_list,   dim3(40), dim3(64), 0, stream, sbox, slvl, ssupp, gmax,
                     lists, mcnt, nbox, narea);
  hipLaunchKernelGGL(k_mask,   dim3(40,4), dim3(256), 0, stream, nbox, narea, mcnt, mask);
  hipLaunchKernelGGL(k_reduce, dim3(40), dim3(64), 0, stream, mask, mcnt, lists, ssupp);
  hipLaunchKernelGGL(k_out,    dim3(NIMG), dim3(256), 0, stream, sbox, sscore, ssupp, out);
}

// Round 3
// 555.717 us; speedup vs baseline: 2.7772x; 1.4881x over previous
//
#include <hip/hip_runtime.h>
#include <math.h>

#define NIMG 8
#define TT   159882
#define KTOT 4507
#define POST 1000
#define NSUB 32

__constant__ int c_n[5]   = {120000,30000,7500,1875,507};
__constant__ int c_off[5] = {0,120000,150000,157500,159375};
__constant__ int c_k[5]   = {1000,1000,1000,1000,507};
__constant__ int c_pos[5] = {0,1000,2000,3000,4000};

__device__ __forceinline__ unsigned fkey(float f){
  unsigned u=__float_as_uint(f);
  return (u&0x80000000u)? ~u : (u|0x80000000u);
}

// ---------------- K0: zero global histograms (first-replay poison safety) -----
__global__ __launch_bounds__(256) void k_zero(unsigned* __restrict__ ghist){
  int i=blockIdx.x*256+threadIdx.x;
  if(i<40*2048) ghist[i]=0u;
}

// ---------------- K1a: distributed radix histogram (one round) ----------------
__global__ __launch_bounds__(256) void k_hist(const float* __restrict__ obj,
    const unsigned* __restrict__ gpref, unsigned* __restrict__ ghist, int rnd){
  const int il=blockIdx.x, sub=blockIdx.y;
  const int img=il/5, lvl=il%5;
  const int n=c_n[lvl], k=c_k[lvl];
  if(k>=n) return;
  const int chunk=(n+NSUB-1)/NSUB;
  const int start=sub*chunk, end=min(start+chunk,n);
  if(start>=end) return;
  const float* o=obj+(size_t)img*TT+c_off[lvl];
  __shared__ unsigned hist[2048];
  const int sh=(rnd==0)?21:(rnd==1)?10:0;
  const int nb=(rnd==2)?1024:2048;
  const unsigned msk=(unsigned)(nb-1);
  const unsigned hiMask=(rnd==0)?0u:(0xFFFFFFFFu<<((rnd==1)?21:10));
  const unsigned prefix=(rnd==0)?0u:gpref[il];
  for(int i=threadIdx.x;i<nb;i+=256) hist[i]=0u;
  __syncthreads();
  for(int i=start+threadIdx.x;i<end;i+=256){
    unsigned key=fkey(o[i]);
    if(rnd==0 || (key&hiMask)==prefix) atomicAdd(&hist[(key>>sh)&msk],1u);
  }
  __syncthreads();
  for(int b=threadIdx.x;b<nb;b+=256){
    unsigned v=hist[b];
    if(v) atomicAdd(&ghist[il*2048+b],v);
  }
}

// ---------------- K1b: pick bucket via parallel suffix-sum, zero hist ---------
__global__ __launch_bounds__(256) void k_scan(unsigned* __restrict__ ghist,
    unsigned* __restrict__ gpref, int* __restrict__ gkrem,
    int* __restrict__ gcnt, int rnd){
  const int il=blockIdx.x, lvl=il%5;
  const int n=c_n[lvl], k=c_k[lvl];
  __shared__ unsigned suf[2049];
  if(k>=n){
    if(rnd==2 && threadIdx.x==0){ gpref[il]=0u; gkrem[il]=0; gcnt[il*2]=0; gcnt[il*2+1]=0; }
    return;
  }
  const int sh=(rnd==0)?21:(rnd==1)?10:0;
  const int nb=(rnd==2)?1024:2048;
  const int kr=(rnd==0)?k:gkrem[il];
  for(int b=threadIdx.x;b<nb;b+=256) suf[b]=ghist[il*2048+b];
  if(threadIdx.x==0) suf[nb]=0u;
  __syncthreads();
  for(int d=1;d<nb;d<<=1){
    unsigned t[8];
    for(int b=threadIdx.x,j=0;b<nb;b+=256,j++) t[j]=(b+d<nb)?suf[b+d]:0u;
    __syncthreads();
    for(int b=threadIdx.x,j=0;b<nb;b+=256,j++) suf[b]+=t[j];
    __syncthreads();
  }
  for(int b=threadIdx.x;b<nb;b+=256){
    if(suf[b]>=(unsigned)kr && suf[b+1]<(unsigned)kr){
      unsigned prevPref=(rnd==0)?0u:gpref[il];
      gpref[il]=prevPref|((unsigned)b<<sh);
      gkrem[il]=kr-(int)suf[b+1];
    }
  }
  for(int b=threadIdx.x;b<2048;b+=256) ghist[il*2048+b]=0u;   // ready for next round/replay
  if(rnd==2 && threadIdx.x==0){ gcnt[il*2]=0; gcnt[il*2+1]=0; }
}

// ---------------- K1c: distributed selection against final threshold ---------
__global__ __launch_bounds__(256) void k_sel(const float* __restrict__ obj,
    const unsigned* __restrict__ gpref, const int* __restrict__ gkrem,
    int* __restrict__ gcnt, int* __restrict__ sel, int* __restrict__ eqbuf){
  const int il=blockIdx.x, sub=blockIdx.y;
  const int img=il/5, lvl=il%5;
  const int n=c_n[lvl], k=c_k[lvl];
  const int chunk=(n+NSUB-1)/NSUB;
  const int start=sub*chunk, end=min(start+chunk,n);
  if(start>=end) return;
  int* s=sel+img*KTOT+c_pos[lvl];
  if(k>=n){
    for(int i=start+threadIdx.x;i<end;i+=256) s[i]=i;
    return;
  }
  const float* o=obj+(size_t)img*TT+c_off[lvl];
  const unsigned t=gpref[il];
  const int krem=gkrem[il];
  for(int i=start+threadIdx.x;i<end;i+=256){
    unsigned key=fkey(o[i]);
    if(key>t){ s[atomicAdd(&gcnt[il*2],1)]=i; }
    else if(key==t && krem>0){ int p=atomicAdd(&gcnt[il*2+1],1); if(p<2048) eqbuf[il*2048+p]=i; }
  }
}

// ---------------- K1d: eq-tiebreak picks + level rank sort --------------------
// Final order is (logit desc, idx asc) -- deterministic regardless of atomic
// insertion order above, reproducing the reference gather order exactly.
__global__ __launch_bounds__(256) void k_sort(const float* __restrict__ obj,
    const int* __restrict__ gkrem, const int* __restrict__ gcnt,
    int* __restrict__ sel, int* __restrict__ eqbuf){
  const int il=blockIdx.x, img=il/5, lvl=il%5;
  const int n=c_n[lvl], k=c_k[lvl];
  const float* o=obj+(size_t)img*TT+c_off[lvl];
  int* s=sel+img*KTOT+c_pos[lvl];
  __shared__ unsigned long long skey[1024];
  if(k<n){
    const int krem=gkrem[il];
    if(krem>0 && threadIdx.x==0){
      int cgt=gcnt[il*2];
      int ceq=min(gcnt[il*2+1],2048);
      int* eq=eqbuf+il*2048;
      for(int r2=0;r2<krem;r2++){
        int mn=0x7fffffff,mi=0;
        for(int j=0;j<ceq;j++) if(eq[j]<mn){mn=eq[j];mi=j;}
        s[cgt+r2]=mn; eq[mi]=0x7fffffff;
      }
    }
    __syncthreads();
  }
  for(int i=threadIdx.x;i<k;i+=256){
    int idx=s[i];
    skey[i]=((unsigned long long)fkey(o[idx])<<32)|(unsigned)(~(unsigned)idx);
  }
  __syncthreads();
  for(int i=threadIdx.x;i<k;i+=256){
    unsigned long long mk=skey[i];
    int rank=0;
    for(int j=0;j<k;j++) rank+=(skey[j]>mk)?1:0;
    int idx=(int)(~(unsigned)(mk&0xFFFFFFFFu));
    s[rank]=idx+c_off[lvl];
  }
}

// ---------------- K2a: decode+clip+score, build global sort keys, image max ----
__global__ __launch_bounds__(256) void k_decode(const float* __restrict__ obj,
    const float* __restrict__ del, const float* __restrict__ anc,
    const int* __restrict__ sel, float* __restrict__ pbox, float* __restrict__ pscore,
    int* __restrict__ plvl, unsigned long long* __restrict__ gkey,
    float* __restrict__ gmax){
  const int img=blockIdx.x;
  __shared__ float smax[256];
  const float BCLIP=(float)4.135166556742356;  // log(1000/16)
  float lm=0.f;
  for(int pos=threadIdx.x;pos<KTOT;pos+=256){
    int lvl = pos<1000?0:pos<2000?1:pos<3000?2:pos<4000?3:4;
    int tdx = sel[img*KTOT+pos];
    float logit = obj[(size_t)img*TT+tdx];
    const float* a=anc+4*(size_t)tdx;
    const float* d=del+((size_t)img*TT+tdx)*4;
    float w=a[2]-a[0], h=a[3]-a[1];
    float cx=a[0]+0.5f*w, cy=a[1]+0.5f*h;
    float dw=fminf(d[2],BCLIP), dh=fminf(d[3],BCLIP);
    float pcx=d[0]*w+cx, pcy=d[1]*h+cy;
    float pw=expf(dw)*w, ph=expf(dh)*h;
    float x1=pcx-0.5f*pw, y1=pcy-0.5f*ph;
    float x2=pcx+0.5f*pw, y2=pcy+0.5f*ph;
    x1=fminf(fmaxf(x1,0.f),800.f); y1=fminf(fmaxf(y1,0.f),800.f);
    x2=fminf(fmaxf(x2,0.f),800.f); y2=fminf(fmaxf(y2,0.f),800.f);
    int valid=(x2-x1>=1e-3f)&&(y2-y1>=1e-3f);
    float sc=1.f/(1.f+expf(-logit));
    float sv=valid? sc : -INFINITY;
    gkey[img*KTOT+pos]=((unsigned long long)fkey(sv)<<32)|(unsigned)(KTOT-1-pos);
    float* pb=pbox+((size_t)img*KTOT+pos)*4;
    pb[0]=x1; pb[1]=y1; pb[2]=x2; pb[3]=y2;
    pscore[img*KTOT+pos]=sc;
    plvl[img*KTOT+pos]=lvl|(valid?0:256);
    lm=fmaxf(lm,fmaxf(fmaxf(x1,y1),fmaxf(x2,y2)));
  }
  smax[threadIdx.x]=lm; __syncthreads();
  for(int st=128;st>0;st>>=1){
    if(threadIdx.x<st) smax[threadIdx.x]=fmaxf(smax[threadIdx.x],smax[threadIdx.x+st]);
    __syncthreads();
  }
  if(threadIdx.x==0) gmax[img]=smax[0];
}

// ---------------- K2b: global rank sort (score desc, pos asc) + scatter -------
__global__ __launch_bounds__(256) void k_rank(const unsigned long long* __restrict__ gkey,
    const float* __restrict__ pbox, const float* __restrict__ pscore,
    const int* __restrict__ plvl,
    float* __restrict__ sbox, float* __restrict__ sscore,
    int* __restrict__ slvl, int* __restrict__ ssupp){
  const int img=blockIdx.x/18, chunk=blockIdx.x%18;
  __shared__ unsigned long long key[KTOT];
  for(int i=threadIdx.x;i<KTOT;i+=256) key[i]=gkey[img*KTOT+i];
  __syncthreads();
  int pos=chunk*256+threadIdx.x;
  if(pos<KTOT){
    unsigned long long mk=key[pos];
    int rank=0;
    for(int j=0;j<KTOT;j++) rank+=(key[j]>mk)?1:0;
    const float* pb=pbox+((size_t)img*KTOT+pos)*4;
    float* sb=sbox+((size_t)img*KTOT+rank)*4;
    sb[0]=pb[0]; sb[1]=pb[1]; sb[2]=pb[2]; sb[3]=pb[3];
    sscore[img*KTOT+rank]=pscore[img*KTOT+pos];
    int lv=plvl[img*KTOT+pos];
    slvl[img*KTOT+rank]=lv&0xFF;
    ssupp[img*KTOT+rank]=(lv>>8)&1;   // invalid -> pre-suppressed
  }
}

// ---------------- K3a: per-(img,level) ordered candidate list (wave ballot) ---
__global__ __launch_bounds__(64) void k_list(const float* __restrict__ sbox,
    const int* __restrict__ slvl, const int* __restrict__ ssupp,
    const float* __restrict__ gmax,
    int* __restrict__ lists, int* __restrict__ mcnt,
    float4* __restrict__ nbox, float* __restrict__ narea){
  const int img=blockIdx.x/5, lvl=blockIdx.x%5;
  const int lane=threadIdx.x;
  int* list = lists + blockIdx.x*1024;
  int base=0;
  for(int t=0;t<KTOT;t+=64){
    int r=t+lane;
    bool pred = (r<KTOT) && (slvl[img*KTOT+r]==lvl) && (ssupp[img*KTOT+r]==0);
    unsigned long long b=__ballot(pred);
    int prefix=__popcll(b & ((1ull<<lane)-1ull));
    if(pred) list[base+prefix]=r;
    base+=__popcll(b);
  }
  if(lane==0) mcnt[blockIdx.x]=base;
  const int m=base;
  const float off=(float)lvl*(gmax[img]+1.0f);   // replicate ref offset math exactly
  for(int i=lane;i<m;i+=64){
    int r=list[i];
    const float* bx=sbox+((size_t)img*KTOT+r)*4;
    float a0=bx[0]+off, a1=bx[1]+off, a2=bx[2]+off, a3=bx[3]+off;
    nbox[blockIdx.x*1024+i]=make_float4(a0,a1,a2,a3);
    narea[blockIdx.x*1024+i]=(a2-a0)*(a3-a1);
  }
}

// ---------------- K3b: parallel pairwise suppression bitmasks -----------------
__global__ __launch_bounds__(256) void k_mask(const float4* __restrict__ nbox,
    const float* __restrict__ narea, const int* __restrict__ mcnt,
    unsigned long long* __restrict__ mask){
  const int il=blockIdx.x, chunk=blockIdx.y;
  const int m=mcnt[il];
  if(chunk*256>=m) return;
  __shared__ float4 sb[1024];
  __shared__ float  sa[1024];
  for(int i=threadIdx.x;i<m;i+=256){ sb[i]=nbox[il*1024+i]; sa[i]=narea[il*1024+i]; }
  __syncthreads();
  const int i=chunk*256+threadIdx.x;
  if(i>=m) return;
  const float4 bi=sb[i]; const float ai=sa[i];
  const int wlast=(m+63)>>6;
  const int wi=i>>6;
  unsigned long long* out = mask + ((size_t)il*1024 + i)*16;
  for(int w=0;w<16;++w){
    unsigned long long bits=0ull;
    if(w>=wi && w<wlast){
      const int jend=min(64, m-w*64);
      for(int jj=0;jj<jend;++jj){
        const float4 bj=sb[w*64+jj];
        float ltx=fmaxf(bi.x,bj.x), lty=fmaxf(bi.y,bj.y);
        float rbx=fminf(bi.z,bj.z), rby=fminf(bi.w,bj.w);
        float wx=fmaxf(rbx-ltx,0.f), wy=fmaxf(rby-lty,0.f);
        float inter=wx*wy;
        float iou=inter/((ai+sa[w*64+jj])-inter);
        bits |= (iou>0.7f)? (1ull<<jj) : 0ull;
      }
      if(w==wi){ int b=i&63; bits &= ~((2ull<<b)-1ull); }
    }
    out[w]=bits;
  }
}

// ---------------- K3c: serial greedy reduce over bitmasks (1 wave/blk) --------
__global__ __launch_bounds__(64) void k_reduce(const unsigned long long* __restrict__ mask,
    const int* __restrict__ mcnt, const int* __restrict__ lists,
    int* __restrict__ ssupp){
  const int il=blockIdx.x, img=il/5;
  const int m=mcnt[il];
  const int lane=threadIdx.x;
  const unsigned long long* M = mask + (size_t)il*1024*16;
  const bool ld = lane<16;
  unsigned long long remv=0ull;
  unsigned long long c0,c1,c2,c3,c4,c5,c6,c7;
  unsigned long long n0,n1,n2,n3,n4,n5,n6,n7;
#define LD(r,b) ((ld && ((b)+(r))<m) ? M[(size_t)((b)+(r))*16+lane] : 0ull)
  c0=LD(0,0); c1=LD(1,0); c2=LD(2,0); c3=LD(3,0);
  c4=LD(4,0); c5=LD(5,0); c6=LD(6,0); c7=LD(7,0);
  for(int g=0;;++g){
    const int nb=(g+1)*8;
    n0=LD(0,nb); n1=LD(1,nb); n2=LD(2,nb); n3=LD(3,nb);
    n4=LD(4,nb); n5=LD(5,nb); n6=LD(6,nb); n7=LD(7,nb);
#define STEP(r,cr) { int i=g*8+(r); if(i<m){ \
    unsigned long long word=__shfl(remv, i>>6); \
    if(((word>>(i&63))&1ull)==0ull) remv|=cr; } }
    STEP(0,c0) STEP(1,c1) STEP(2,c2) STEP(3,c3)
    STEP(4,c4) STEP(5,c5) STEP(6,c6) STEP(7,c7)
#undef STEP
    if(nb>=m) break;
    c0=n0; c1=n1; c2=n2; c3=n3; c4=n4; c5=n5; c6=n6; c7=n7;
  }
#undef LD
  const int* list = lists + il*1024;
  for(int t=0;t<m;t+=64){
    int i=t+lane;
    unsigned long long word=__shfl(remv, (i<m? i:0)>>6);
    if(i<m && ((word>>(i&63))&1ull)) ssupp[img*KTOT+list[i]]=1;
  }
}

// ---------------- K4: compact first 1000 survivors per image ------------------
__global__ __launch_bounds__(256) void k_out(const float* __restrict__ sbox,
    const float* __restrict__ sscore, const int* __restrict__ ssupp,
    float* __restrict__ out){
  const int img=blockIdx.x;
  __shared__ unsigned short list[POST];
  __shared__ int s_c;
  if(threadIdx.x<64){
    int base=0;
    for(int t=0;t<KTOT && base<POST;t+=64){
      int r=t+threadIdx.x;
      bool pred = (r<KTOT) && (ssupp[img*KTOT+r]==0);
      unsigned long long b=__ballot(pred);
      int pre=__popcll(b & ((1ull<<threadIdx.x)-1ull));
      if(pred && base+pre<POST) list[base+pre]=(unsigned short)r;
      base+=__popcll(b);
    }
    if(threadIdx.x==0) s_c=min(base,POST);
  }
  __syncthreads();
  const int c=s_c;
  for(int o=threadIdx.x;o<POST;o+=256){
    float* row=out+((size_t)img*POST+o)*5;
    if(o<c){
      int r=list[o];
      const float* b=sbox+((size_t)img*KTOT+r)*4;
      row[0]=b[0]; row[1]=b[1]; row[2]=b[2]; row[3]=b[3];
      row[4]=sscore[img*KTOT+r];
    } else {
      row[0]=0.f; row[1]=0.f; row[2]=0.f; row[3]=0.f; row[4]=0.f;
    }
  }
}

extern "C" void kernel_launch(void* const* d_in, const int* in_sizes, int n_in,
                              void* d_out, int out_size, void* d_ws, size_t ws_size,
                              hipStream_t stream){
  const float* obj=(const float*)d_in[0];
  const float* del=(const float*)d_in[1];
  const float* anc=(const float*)d_in[2];
  float* out=(float*)d_out;

  char* w=(char*)d_ws;
  size_t off=0;
  auto alloc=[&](size_t bytes)->void*{
    void* p=w+off; off+=(bytes+255)&~(size_t)255; return p;
  };
  int*  sel    =(int*)  alloc(sizeof(int)*NIMG*KTOT);
  float* pbox  =(float*)alloc(sizeof(float)*NIMG*KTOT*4);
  float* pscore=(float*)alloc(sizeof(float)*NIMG*KTOT);
  int*  plvl   =(int*)  alloc(sizeof(int)*NIMG*KTOT);
  unsigned long long* gkey=(unsigned long long*)alloc(sizeof(unsigned long long)*NIMG*KTOT);
  float* sbox  =(float*)alloc(sizeof(float)*NIMG*KTOT*4);
  float* sscore=(float*)alloc(sizeof(float)*NIMG*KTOT);
  int*  slvl   =(int*)  alloc(sizeof(int)*NIMG*KTOT);
  int*  ssupp  =(int*)  alloc(sizeof(int)*NIMG*KTOT);
  float* gmax  =(float*)alloc(sizeof(float)*NIMG);
  int*  eqbuf  =(int*)  alloc(sizeof(int)*40*2048);
  int*  lists  =(int*)  alloc(sizeof(int)*40*1024);
  int*  mcnt   =(int*)  alloc(sizeof(int)*40);
  float4* nbox =(float4*)alloc(sizeof(float4)*40*1024);
  float* narea =(float*)alloc(sizeof(float)*40*1024);
  unsigned long long* mask=(unsigned long long*)alloc(sizeof(unsigned long long)*40*1024*16);
  unsigned* ghist=(unsigned*)alloc(sizeof(unsigned)*40*2048);
  unsigned* gpref=(unsigned*)alloc(sizeof(unsigned)*40);
  int*  gkrem  =(int*)  alloc(sizeof(int)*40);
  int*  gcnt   =(int*)  alloc(sizeof(int)*80);

  hipLaunchKernelGGL(k_zero,   dim3((40*2048+255)/256), dim3(256), 0, stream, ghist);
  for(int r=0;r<3;r++){
    hipLaunchKernelGGL(k_hist, dim3(40,NSUB), dim3(256), 0, stream, obj, gpref, ghist, r);
    hipLaunchKernelGGL(k_scan, dim3(40), dim3(256), 0, stream, ghist, gpref, gkrem, gcnt, r);
  }
  hipLaunchKernelGGL(k_sel,    dim3(40,NSUB), dim3(256), 0, stream, obj, gpref, gkrem,
                     gcnt, sel, eqbuf);
  hipLaunchKernelGGL(k_sort,   dim3(40), dim3(256), 0, stream, obj, gkrem, gcnt, sel, eqbuf);
  hipLaunchKernelGGL(k_decode, dim3(NIMG), dim3(256), 0, stream, obj, del, anc, sel,
                     pbox, pscore, plvl, gkey, gmax);
  hipLaunchKernelGGL(k_rank,   dim3(NIMG*18), dim3(256), 0, stream, gkey, pbox, pscore,
                     plvl, sbox, sscore, slvl, ssupp);
  hipLaunchKernelGGL(k_list,   dim3(40), dim3(64), 0, stream, sbox, slvl, ssupp, gmax,
                     lists, mcnt, nbox, narea);
  hipLaunchKernelGGL(k_mask,   dim3(40,4), dim3(256), 0, stream, nbox, narea, mcnt, mask);
  hipLaunchKernelGGL(k_reduce, dim3(40), dim3(64), 0, stream, mask, mcnt, lists, ssupp);
  hipLaunchKernelGGL(k_out,    dim3(NIMG), dim3(256), 0, stream, sbox, sscore, ssupp, out);
}

// Round 4
// 480.032 us; speedup vs baseline: 3.2150x; 1.1577x over previous
//
#include <hip/hip_runtime.h>
#include <math.h>

#define NIMG 8
#define TT   159882
#define KTOT 4507
#define POST 1000
#define NSUB 32

__constant__ int c_n[5]   = {120000,30000,7500,1875,507};
__constant__ int c_off[5] = {0,120000,150000,157500,159375};
__constant__ int c_k[5]   = {1000,1000,1000,1000,507};
__constant__ int c_pos[5] = {0,1000,2000,3000,4000};

__device__ __forceinline__ unsigned fkey(float f){
  unsigned u=__float_as_uint(f);
  return (u&0x80000000u)? ~u : (u|0x80000000u);
}

// ---------------- K0: zero global histograms (first-replay poison safety) -----
__global__ __launch_bounds__(256) void k_zero(unsigned* __restrict__ ghist){
  int i=blockIdx.x*256+threadIdx.x;
  if(i<40*2048) ghist[i]=0u;
}

// ---------------- K1a: distributed radix histogram (one round) ----------------
template<int RND>
__global__ __launch_bounds__(256) void k_hist(const float* __restrict__ obj,
    const unsigned* __restrict__ gpref, unsigned* __restrict__ ghist){
  constexpr int sh=(RND==0)?21:(RND==1)?10:0;
  constexpr int nb=(RND==2)?1024:2048;
  constexpr unsigned msk=(unsigned)(nb-1);
  const int il=blockIdx.x, sub=blockIdx.y;
  const int img=il/5, lvl=il%5;
  const int n=c_n[lvl], k=c_k[lvl];
  if(k>=n) return;
  const int chunk=(n+NSUB-1)/NSUB;
  const int start=sub*chunk, end=min(start+chunk,n);
  if(start>=end) return;
  const float* o=obj+(size_t)img*TT+c_off[lvl];
  __shared__ unsigned hist[2048];
  const unsigned prefix=(RND==0)?0u:gpref[il];
  for(int i=threadIdx.x;i<nb;i+=256) hist[i]=0u;
  __syncthreads();
  for(int i=start+threadIdx.x;i<end;i+=256){
    unsigned key=fkey(o[i]);
    if(RND==0){
      atomicAdd(&hist[(key>>sh)&msk],1u);
    } else {
      constexpr unsigned hiMask=0xFFFFFFFFu<<((RND==1)?21:10);
      if((key&hiMask)==prefix) atomicAdd(&hist[(key>>sh)&msk],1u);
    }
  }
  __syncthreads();
  for(int b=threadIdx.x;b<nb;b+=256){
    unsigned v=hist[b];
    if(v) atomicAdd(&ghist[il*2048+b],v);
  }
}

// ---------------- K1b: pick bucket via register suffix-sum + LDS tree ---------
template<int RND>
__global__ __launch_bounds__(256) void k_scan(unsigned* __restrict__ ghist,
    unsigned* __restrict__ gpref, int* __restrict__ gkrem,
    int* __restrict__ gcnt){
  constexpr int sh=(RND==0)?21:(RND==1)?10:0;
  constexpr int nb=(RND==2)?1024:2048;
  constexpr int C=nb/256;
  const int il=blockIdx.x, lvl=il%5;
  const int n=c_n[lvl], k=c_k[lvl];
  const int t=threadIdx.x;
  __shared__ unsigned tot[256];
  if(k>=n){
    if(RND==2 && t==0){ gpref[il]=0u; gkrem[il]=0; gcnt[il*2]=0; gcnt[il*2+1]=0; }
    return;
  }
  const int kr=(RND==0)?k:gkrem[il];
  unsigned v[C];
#pragma unroll
  for(int i=0;i<C;i++) v[i]=ghist[il*2048+t*C+i];
#pragma unroll
  for(int i=C-2;i>=0;i--) v[i]+=v[i+1];          // local suffix sum (registers)
  tot[t]=v[0];
  __syncthreads();
#pragma unroll
  for(int d=1;d<256;d<<=1){                       // inclusive suffix scan of totals
    unsigned add=(t+d<256)?tot[t+d]:0u;
    __syncthreads();
    tot[t]+=add;
    __syncthreads();
  }
  unsigned tail=(t<255)?tot[t+1]:0u;
#pragma unroll
  for(int i=0;i<C;i++){
    unsigned suf=v[i]+tail;
    unsigned sufn=((i<C-1)?v[i+1]:0u)+tail;
    if(suf>=(unsigned)kr && sufn<(unsigned)kr){
      unsigned prevPref=(RND==0)?0u:gpref[il];
      gpref[il]=prevPref|((unsigned)(t*C+i)<<sh);
      gkrem[il]=kr-(int)sufn;
    }
  }
  for(int b=t;b<2048;b+=256) ghist[il*2048+b]=0u; // ready for next round/replay
  if(RND==2 && t==0){ gcnt[il*2]=0; gcnt[il*2+1]=0; }
}

// ---------------- K1c: distributed selection against final threshold ---------
__global__ __launch_bounds__(256) void k_sel(const float* __restrict__ obj,
    const unsigned* __restrict__ gpref, const int* __restrict__ gkrem,
    int* __restrict__ gcnt, int* __restrict__ sel, int* __restrict__ eqbuf){
  const int il=blockIdx.x, sub=blockIdx.y;
  const int img=il/5, lvl=il%5;
  const int n=c_n[lvl], k=c_k[lvl];
  const int chunk=(n+NSUB-1)/NSUB;
  const int start=sub*chunk, end=min(start+chunk,n);
  if(start>=end) return;
  int* s=sel+img*KTOT+c_pos[lvl];
  if(k>=n){
    for(int i=start+threadIdx.x;i<end;i+=256) s[i]=i;
    return;
  }
  const float* o=obj+(size_t)img*TT+c_off[lvl];
  const unsigned t=gpref[il];
  const int krem=gkrem[il];
  for(int i=start+threadIdx.x;i<end;i+=256){
    unsigned key=fkey(o[i]);
    if(key>t){ s[atomicAdd(&gcnt[il*2],1)]=i; }
    else if(key==t && krem>0){ int p=atomicAdd(&gcnt[il*2+1],1); if(p<2048) eqbuf[il*2048+p]=i; }
  }
}

// ---------------- K1d: eq-tiebreak picks + level rank sort --------------------
__global__ __launch_bounds__(256) void k_sort(const float* __restrict__ obj,
    const int* __restrict__ gkrem, const int* __restrict__ gcnt,
    int* __restrict__ sel, int* __restrict__ eqbuf){
  const int il=blockIdx.x, img=il/5, lvl=il%5;
  const int n=c_n[lvl], k=c_k[lvl];
  const float* o=obj+(size_t)img*TT+c_off[lvl];
  int* s=sel+img*KTOT+c_pos[lvl];
  __shared__ unsigned long long skey[1024];
  if(k<n){
    const int krem=gkrem[il];
    if(krem>0 && threadIdx.x==0){
      int cgt=gcnt[il*2];
      int ceq=min(gcnt[il*2+1],2048);
      int* eq=eqbuf+il*2048;
      for(int r2=0;r2<krem;r2++){
        int mn=0x7fffffff,mi=0;
        for(int j=0;j<ceq;j++) if(eq[j]<mn){mn=eq[j];mi=j;}
        s[cgt+r2]=mn; eq[mi]=0x7fffffff;
      }
    }
    __syncthreads();
  }
  for(int i=threadIdx.x;i<k;i+=256){
    int idx=s[i];
    skey[i]=((unsigned long long)fkey(o[idx])<<32)|(unsigned)(~(unsigned)idx);
  }
  __syncthreads();
  for(int i=threadIdx.x;i<k;i+=256){
    unsigned long long mk=skey[i];
    int rank=0;
    for(int j=0;j<k;j++) rank+=(skey[j]>mk)?1:0;
    int idx=(int)(~(unsigned)(mk&0xFFFFFFFFu));
    s[rank]=idx+c_off[lvl];
  }
}

// ---------------- K2a: decode+clip+score, build global sort keys, image max ----
__global__ __launch_bounds__(256) void k_decode(const float* __restrict__ obj,
    const float* __restrict__ del, const float* __restrict__ anc,
    const int* __restrict__ sel, float* __restrict__ pbox, float* __restrict__ pscore,
    int* __restrict__ plvl, unsigned long long* __restrict__ gkey,
    float* __restrict__ gmax){
  const int img=blockIdx.x;
  __shared__ float smax[256];
  const float BCLIP=(float)4.135166556742356;  // log(1000/16)
  float lm=0.f;
  for(int pos=threadIdx.x;pos<KTOT;pos+=256){
    int lvl = pos<1000?0:pos<2000?1:pos<3000?2:pos<4000?3:4;
    int tdx = sel[img*KTOT+pos];
    float logit = obj[(size_t)img*TT+tdx];
    const float* a=anc+4*(size_t)tdx;
    const float* d=del+((size_t)img*TT+tdx)*4;
    float w=a[2]-a[0], h=a[3]-a[1];
    float cx=a[0]+0.5f*w, cy=a[1]+0.5f*h;
    float dw=fminf(d[2],BCLIP), dh=fminf(d[3],BCLIP);
    float pcx=d[0]*w+cx, pcy=d[1]*h+cy;
    float pw=expf(dw)*w, ph=expf(dh)*h;
    float x1=pcx-0.5f*pw, y1=pcy-0.5f*ph;
    float x2=pcx+0.5f*pw, y2=pcy+0.5f*ph;
    x1=fminf(fmaxf(x1,0.f),800.f); y1=fminf(fmaxf(y1,0.f),800.f);
    x2=fminf(fmaxf(x2,0.f),800.f); y2=fminf(fmaxf(y2,0.f),800.f);
    int valid=(x2-x1>=1e-3f)&&(y2-y1>=1e-3f);
    float sc=1.f/(1.f+expf(-logit));
    float sv=valid? sc : -INFINITY;
    gkey[img*KTOT+pos]=((unsigned long long)fkey(sv)<<32)|(unsigned)(KTOT-1-pos);
    float* pb=pbox+((size_t)img*KTOT+pos)*4;
    pb[0]=x1; pb[1]=y1; pb[2]=x2; pb[3]=y2;
    pscore[img*KTOT+pos]=sc;
    plvl[img*KTOT+pos]=lvl|(valid?0:256);
    lm=fmaxf(lm,fmaxf(fmaxf(x1,y1),fmaxf(x2,y2)));
  }
  smax[threadIdx.x]=lm; __syncthreads();
  for(int st=128;st>0;st>>=1){
    if(threadIdx.x<st) smax[threadIdx.x]=fmaxf(smax[threadIdx.x],smax[threadIdx.x+st]);
    __syncthreads();
  }
  if(threadIdx.x==0) gmax[img]=smax[0];
}

// ---------------- K2b: global rank sort (score desc, pos asc) + scatter -------
__global__ __launch_bounds__(256) void k_rank(const unsigned long long* __restrict__ gkey,
    const float* __restrict__ pbox, const float* __restrict__ pscore,
    const int* __restrict__ plvl,
    float* __restrict__ sbox, float* __restrict__ sscore,
    int* __restrict__ slvl, int* __restrict__ ssupp){
  const int img=blockIdx.x/18, chunk=blockIdx.x%18;
  __shared__ unsigned long long key[KTOT];
  for(int i=threadIdx.x;i<KTOT;i+=256) key[i]=gkey[img*KTOT+i];
  __syncthreads();
  int pos=chunk*256+threadIdx.x;
  if(pos<KTOT){
    unsigned long long mk=key[pos];
    int rank=0;
    for(int j=0;j<KTOT;j++) rank+=(key[j]>mk)?1:0;
    const float* pb=pbox+((size_t)img*KTOT+pos)*4;
    float* sb=sbox+((size_t)img*KTOT+rank)*4;
    sb[0]=pb[0]; sb[1]=pb[1]; sb[2]=pb[2]; sb[3]=pb[3];
    sscore[img*KTOT+rank]=pscore[img*KTOT+pos];
    int lv=plvl[img*KTOT+pos];
    slvl[img*KTOT+rank]=lv&0xFF;
    ssupp[img*KTOT+rank]=(lv>>8)&1;   // invalid -> pre-suppressed
  }
}

// ---------------- K3a: per-(img,level) ordered candidate list (wave ballot) ---
__global__ __launch_bounds__(64) void k_list(const float* __restrict__ sbox,
    const int* __restrict__ slvl, const int* __restrict__ ssupp,
    const float* __restrict__ gmax,
    int* __restrict__ lists, int* __restrict__ mcnt,
    float4* __restrict__ nbox, float* __restrict__ narea){
  const int img=blockIdx.x/5, lvl=blockIdx.x%5;
  const int lane=threadIdx.x;
  int* list = lists + blockIdx.x*1024;
  int base=0;
  for(int t=0;t<KTOT;t+=64){
    int r=t+lane;
    bool pred = (r<KTOT) && (slvl[img*KTOT+r]==lvl) && (ssupp[img*KTOT+r]==0);
    unsigned long long b=__ballot(pred);
    int prefix=__popcll(b & ((1ull<<lane)-1ull));
    if(pred) list[base+prefix]=r;
    base+=__popcll(b);
  }
  if(lane==0) mcnt[blockIdx.x]=base;
  const int m=base;
  const float off=(float)lvl*(gmax[img]+1.0f);   // replicate ref offset math exactly
  for(int i=lane;i<m;i+=64){
    int r=list[i];
    const float* bx=sbox+((size_t)img*KTOT+r)*4;
    float a0=bx[0]+off, a1=bx[1]+off, a2=bx[2]+off, a3=bx[3]+off;
    nbox[blockIdx.x*1024+i]=make_float4(a0,a1,a2,a3);
    narea[blockIdx.x*1024+i]=(a2-a0)*(a3-a1);
  }
}

// ---------------- K3b: parallel pairwise suppression bitmasks -----------------
__global__ __launch_bounds__(256) void k_mask(const float4* __restrict__ nbox,
    const float* __restrict__ narea, const int* __restrict__ mcnt,
    unsigned long long* __restrict__ mask){
  const int il=blockIdx.x, chunk=blockIdx.y;
  const int m=mcnt[il];
  if(chunk*256>=m) return;
  __shared__ float4 sb[1024];
  __shared__ float  sa[1024];
  for(int i=threadIdx.x;i<m;i+=256){ sb[i]=nbox[il*1024+i]; sa[i]=narea[il*1024+i]; }
  __syncthreads();
  const int i=chunk*256+threadIdx.x;
  if(i>=m) return;
  const float4 bi=sb[i]; const float ai=sa[i];
  const int wlast=(m+63)>>6;
  const int wi=i>>6;
  unsigned long long* out = mask + ((size_t)il*1024 + i)*16;
  for(int w=0;w<16;++w){
    unsigned long long bits=0ull;
    if(w>=wi && w<wlast){
      const int jend=min(64, m-w*64);
      for(int jj=0;jj<jend;++jj){
        const float4 bj=sb[w*64+jj];
        float ltx=fmaxf(bi.x,bj.x), lty=fmaxf(bi.y,bj.y);
        float rbx=fminf(bi.z,bj.z), rby=fminf(bi.w,bj.w);
        float wx=fmaxf(rbx-ltx,0.f), wy=fmaxf(rby-lty,0.f);
        float inter=wx*wy;
        float iou=inter/((ai+sa[w*64+jj])-inter);
        bits |= (iou>0.7f)? (1ull<<jj) : 0ull;
      }
      if(w==wi){ int b=i&63; bits &= ~((2ull<<b)-1ull); }
    }
    out[w]=bits;
  }
}

// ---------------- K3c: greedy reduce; lane-local decisions, 1 shfl / 8 elems --
__global__ __launch_bounds__(64) void k_reduce(const unsigned long long* __restrict__ mask,
    const int* __restrict__ mcnt, const int* __restrict__ lists,
    int* __restrict__ ssupp){
  const int il=blockIdx.x, img=il/5;
  const int m=mcnt[il];
  const int lane=threadIdx.x;
  const unsigned long long* M = mask + (size_t)il*1024*16;
  const bool ld = lane<16;
  unsigned long long remv=0ull;
  unsigned long long c0,c1,c2,c3,c4,c5,c6,c7;
  unsigned long long n0,n1,n2,n3,n4,n5,n6,n7;
#define LD(r,b) ((ld && ((b)+(r))<m) ? M[(size_t)((b)+(r))*16+lane] : 0ull)
  c0=LD(0,0); c1=LD(1,0); c2=LD(2,0); c3=LD(3,0);
  c4=LD(4,0); c5=LD(5,0); c6=LD(6,0); c7=LD(7,0);
  for(int g=0;;++g){
    const int nb=(g+1)*8;
    n0=LD(0,nb); n1=LD(1,nb); n2=LD(2,nb); n3=LD(3,nb);
    n4=LD(4,nb); n5=LD(5,nb); n6=LD(6,nb); n7=LD(7,nb);
    // lane-local simulated decisions for this group of 8 (chunk w = base>>6):
    // every lane pretends to be the decision lane using its own remv window and
    // its own row segments; only lane w's result is authoritative.
    const int base=g*8;
    const int w=base>>6;
    const int bb=base&63;
    unsigned t8=(unsigned)(remv>>bb);
    unsigned am=0u;
#define DEC(r,cr) { unsigned alive=1u^((t8>>(r))&1u); am|=alive<<(r); \
                    if(alive) t8|=(unsigned)((cr)>>bb); }
    DEC(0,c0) DEC(1,c1) DEC(2,c2) DEC(3,c3)
    DEC(4,c4) DEC(5,c5) DEC(6,c6) DEC(7,c7)
#undef DEC
    const int rem=m-base;
    unsigned vm=(rem>=8)?0xffu:((rem<=0)?0u:((1u<<rem)-1u));
    am&=vm;
    unsigned am_w=(unsigned)__shfl((int)am, w);
    if(am_w&1u)   remv|=c0;
    if(am_w&2u)   remv|=c1;
    if(am_w&4u)   remv|=c2;
    if(am_w&8u)   remv|=c3;
    if(am_w&16u)  remv|=c4;
    if(am_w&32u)  remv|=c5;
    if(am_w&64u)  remv|=c6;
    if(am_w&128u) remv|=c7;
    if(nb>=m) break;
    c0=n0; c1=n1; c2=n2; c3=n3; c4=n4; c5=n5; c6=n6; c7=n7;
  }
#undef LD
  const int* list = lists + il*1024;
  for(int t=0;t<m;t+=64){
    int i=t+lane;
    unsigned long long word=__shfl(remv, (i<m? i:0)>>6);
    if(i<m && ((word>>(i&63))&1ull)) ssupp[img*KTOT+list[i]]=1;
  }
}

// ---------------- K4: compact first 1000 survivors per image ------------------
__global__ __launch_bounds__(256) void k_out(const float* __restrict__ sbox,
    const float* __restrict__ sscore, const int* __restrict__ ssupp,
    float* __restrict__ out){
  const int img=blockIdx.x;
  __shared__ unsigned short list[POST];
  __shared__ int s_c;
  if(threadIdx.x<64){
    int base=0;
    for(int t=0;t<KTOT && base<POST;t+=64){
      int r=t+threadIdx.x;
      bool pred = (r<KTOT) && (ssupp[img*KTOT+r]==0);
      unsigned long long b=__ballot(pred);
      int pre=__popcll(b & ((1ull<<threadIdx.x)-1ull));
      if(pred && base+pre<POST) list[base+pre]=(unsigned short)r;
      base+=__popcll(b);
    }
    if(threadIdx.x==0) s_c=min(base,POST);
  }
  __syncthreads();
  const int c=s_c;
  for(int o=threadIdx.x;o<POST;o+=256){
    float* row=out+((size_t)img*POST+o)*5;
    if(o<c){
      int r=list[o];
      const float* b=sbox+((size_t)img*KTOT+r)*4;
      row[0]=b[0]; row[1]=b[1]; row[2]=b[2]; row[3]=b[3];
      row[4]=sscore[img*KTOT+r];
    } else {
      row[0]=0.f; row[1]=0.f; row[2]=0.f; row[3]=0.f; row[4]=0.f;
    }
  }
}

extern "C" void kernel_launch(void* const* d_in, const int* in_sizes, int n_in,
                              void* d_out, int out_size, void* d_ws, size_t ws_size,
                              hipStream_t stream){
  const float* obj=(const float*)d_in[0];
  const float* del=(const float*)d_in[1];
  const float* anc=(const float*)d_in[2];
  float* out=(float*)d_out;

  char* w=(char*)d_ws;
  size_t off=0;
  auto alloc=[&](size_t bytes)->void*{
    void* p=w+off; off+=(bytes+255)&~(size_t)255; return p;
  };
  int*  sel    =(int*)  alloc(sizeof(int)*NIMG*KTOT);
  float* pbox  =(float*)alloc(sizeof(float)*NIMG*KTOT*4);
  float* pscore=(float*)alloc(sizeof(float)*NIMG*KTOT);
  int*  plvl   =(int*)  alloc(sizeof(int)*NIMG*KTOT);
  unsigned long long* gkey=(unsigned long long*)alloc(sizeof(unsigned long long)*NIMG*KTOT);
  float* sbox  =(float*)alloc(sizeof(float)*NIMG*KTOT*4);
  float* sscore=(float*)alloc(sizeof(float)*NIMG*KTOT);
  int*  slvl   =(int*)  alloc(sizeof(int)*NIMG*KTOT);
  int*  ssupp  =(int*)  alloc(sizeof(int)*NIMG*KTOT);
  float* gmax  =(float*)alloc(sizeof(float)*NIMG);
  int*  eqbuf  =(int*)  alloc(sizeof(int)*40*2048);
  int*  lists  =(int*)  alloc(sizeof(int)*40*1024);
  int*  mcnt   =(int*)  alloc(sizeof(int)*40);
  float4* nbox =(float4*)alloc(sizeof(float4)*40*1024);
  float* narea =(float*)alloc(sizeof(float)*40*1024);
  unsigned long long* mask=(unsigned long long*)alloc(sizeof(unsigned long long)*40*1024*16);
  unsigned* ghist=(unsigned*)alloc(sizeof(unsigned)*40*2048);
  unsigned* gpref=(unsigned*)alloc(sizeof(unsigned)*40);
  int*  gkrem  =(int*)  alloc(sizeof(int)*40);
  int*  gcnt   =(int*)  alloc(sizeof(int)*80);

  hipLaunchKernelGGL(k_zero,    dim3((40*2048+255)/256), dim3(256), 0, stream, ghist);
  hipLaunchKernelGGL(k_hist<0>, dim3(40,NSUB), dim3(256), 0, stream, obj, gpref, ghist);
  hipLaunchKernelGGL(k_scan<0>, dim3(40), dim3(256), 0, stream, ghist, gpref, gkrem, gcnt);
  hipLaunchKernelGGL(k_hist<1>, dim3(40,NSUB), dim3(256), 0, stream, obj, gpref, ghist);
  hipLaunchKernelGGL(k_scan<1>, dim3(40), dim3(256), 0, stream, ghist, gpref, gkrem, gcnt);
  hipLaunchKernelGGL(k_hist<2>, dim3(40,NSUB), dim3(256), 0, stream, obj, gpref, ghist);
  hipLaunchKernelGGL(k_scan<2>, dim3(40), dim3(256), 0, stream, ghist, gpref, gkrem, gcnt);
  hipLaunchKernelGGL(k_sel,    dim3(40,NSUB), dim3(256), 0, stream, obj, gpref, gkrem,
                     gcnt, sel, eqbuf);
  hipLaunchKernelGGL(k_sort,   dim3(40), dim3(256), 0, stream, obj, gkrem, gcnt, sel, eqbuf);
  hipLaunchKernelGGL(k_decode, dim3(NIMG), dim3(256), 0, stream, obj, del, anc, sel,
                     pbox, pscore, plvl, gkey, gmax);
  hipLaunchKernelGGL(k_rank,   dim3(NIMG*18), dim3(256), 0, stream, gkey, pbox, pscore,
                     plvl, sbox, sscore, slvl, ssupp);
  hipLaunchKernelGGL(k_list,   dim3(40), dim3(64), 0, stream, sbox, slvl, ssupp, gmax,
                     lists, mcnt, nbox, narea);
  hipLaunchKernelGGL(k_mask,   dim3(40,4), dim3(256), 0, stream, nbox, narea, mcnt, mask);
  hipLaunchKernelGGL(k_reduce, dim3(40), dim3(64), 0, stream, mask, mcnt, lists, ssupp);
  hipLaunchKernelGGL(k_out,    dim3(NIMG), dim3(256), 0, stream, sbox, sscore, ssupp, out);
}

// Round 5
// 408.199 us; speedup vs baseline: 3.7808x; 1.1760x over previous
//
#include <hip/hip_runtime.h>
#include <math.h>

#define NIMG 8
#define TT   159882
#define KTOT 4507
#define POST 1000
#define NSUB 32

__constant__ int c_n[5]   = {120000,30000,7500,1875,507};
__constant__ int c_off[5] = {0,120000,150000,157500,159375};
__constant__ int c_k[5]   = {1000,1000,1000,1000,507};
__constant__ int c_pos[5] = {0,1000,2000,3000,4000};

__device__ __forceinline__ unsigned fkey(float f){
  unsigned u=__float_as_uint(f);
  return (u&0x80000000u)? ~u : (u|0x80000000u);
}

// ---------------- K0: zero global histograms (first-replay poison safety) -----
__global__ __launch_bounds__(256) void k_zero(unsigned* __restrict__ ghist){
  int i=blockIdx.x*256+threadIdx.x;
  if(i<40*2048) ghist[i]=0u;
}

// ---------------- K1a: distributed radix histogram (one round) ----------------
template<int RND>
__global__ __launch_bounds__(256) void k_hist(const float* __restrict__ obj,
    const unsigned* __restrict__ gpref, unsigned* __restrict__ ghist){
  constexpr int sh=(RND==0)?21:(RND==1)?10:0;
  constexpr int nb=(RND==2)?1024:2048;
  constexpr unsigned msk=(unsigned)(nb-1);
  const int il=blockIdx.x, sub=blockIdx.y;
  const int img=il/5, lvl=il%5;
  const int n=c_n[lvl], k=c_k[lvl];
  if(k>=n) return;
  const int chunk=(n+NSUB-1)/NSUB;
  const int start=sub*chunk, end=min(start+chunk,n);
  if(start>=end) return;
  const float* o=obj+(size_t)img*TT+c_off[lvl];
  __shared__ unsigned hist[2048];
  const unsigned prefix=(RND==0)?0u:gpref[il];
  for(int i=threadIdx.x;i<nb;i+=256) hist[i]=0u;
  __syncthreads();
  for(int i=start+threadIdx.x;i<end;i+=256){
    unsigned key=fkey(o[i]);
    if(RND==0){
      atomicAdd(&hist[(key>>sh)&msk],1u);
    } else {
      constexpr unsigned hiMask=0xFFFFFFFFu<<((RND==1)?21:10);
      if((key&hiMask)==prefix) atomicAdd(&hist[(key>>sh)&msk],1u);
    }
  }
  __syncthreads();
  for(int b=threadIdx.x;b<nb;b+=256){
    unsigned v=hist[b];
    if(v) atomicAdd(&ghist[il*2048+b],v);
  }
}

// ---------------- K1b: pick bucket via register suffix-sum + LDS tree ---------
template<int RND>
__global__ __launch_bounds__(256) void k_scan(unsigned* __restrict__ ghist,
    unsigned* __restrict__ gpref, int* __restrict__ gkrem,
    int* __restrict__ gcnt){
  constexpr int sh=(RND==0)?21:(RND==1)?10:0;
  constexpr int nb=(RND==2)?1024:2048;
  constexpr int C=nb/256;
  const int il=blockIdx.x, lvl=il%5;
  const int n=c_n[lvl], k=c_k[lvl];
  const int t=threadIdx.x;
  __shared__ unsigned tot[256];
  if(k>=n){
    if(RND==2 && t==0){ gpref[il]=0u; gkrem[il]=0; gcnt[il*2]=0; gcnt[il*2+1]=0; }
    return;
  }
  const int kr=(RND==0)?k:gkrem[il];
  unsigned v[C];
#pragma unroll
  for(int i=0;i<C;i++) v[i]=ghist[il*2048+t*C+i];
#pragma unroll
  for(int i=C-2;i>=0;i--) v[i]+=v[i+1];          // local suffix sum (registers)
  tot[t]=v[0];
  __syncthreads();
#pragma unroll
  for(int d=1;d<256;d<<=1){                       // inclusive suffix scan of totals
    unsigned add=(t+d<256)?tot[t+d]:0u;
    __syncthreads();
    tot[t]+=add;
    __syncthreads();
  }
  unsigned tail=(t<255)?tot[t+1]:0u;
#pragma unroll
  for(int i=0;i<C;i++){
    unsigned suf=v[i]+tail;
    unsigned sufn=((i<C-1)?v[i+1]:0u)+tail;
    if(suf>=(unsigned)kr && sufn<(unsigned)kr){
      unsigned prevPref=(RND==0)?0u:gpref[il];
      gpref[il]=prevPref|((unsigned)(t*C+i)<<sh);
      gkrem[il]=kr-(int)sufn;
    }
  }
  for(int b=t;b<2048;b+=256) ghist[il*2048+b]=0u; // ready for next round/replay
  if(RND==2 && t==0){ gcnt[il*2]=0; gcnt[il*2+1]=0; }
}

// ---------------- K1c: distributed selection against final threshold ---------
__global__ __launch_bounds__(256) void k_sel(const float* __restrict__ obj,
    const unsigned* __restrict__ gpref, const int* __restrict__ gkrem,
    int* __restrict__ gcnt, int* __restrict__ sel, int* __restrict__ eqbuf){
  const int il=blockIdx.x, sub=blockIdx.y;
  const int img=il/5, lvl=il%5;
  const int n=c_n[lvl], k=c_k[lvl];
  const int chunk=(n+NSUB-1)/NSUB;
  const int start=sub*chunk, end=min(start+chunk,n);
  if(start>=end) return;
  int* s=sel+img*KTOT+c_pos[lvl];
  if(k>=n){
    for(int i=start+threadIdx.x;i<end;i+=256) s[i]=i;
    return;
  }
  const float* o=obj+(size_t)img*TT+c_off[lvl];
  const unsigned t=gpref[il];
  const int krem=gkrem[il];
  for(int i=start+threadIdx.x;i<end;i+=256){
    unsigned key=fkey(o[i]);
    if(key>t){ s[atomicAdd(&gcnt[il*2],1)]=i; }
    else if(key==t && krem>0){ int p=atomicAdd(&gcnt[il*2+1],1); if(p<2048) eqbuf[il*2048+p]=i; }
  }
}

// ---------------- K1d: eq-tiebreak picks + level rank sort --------------------
__global__ __launch_bounds__(256) void k_sort(const float* __restrict__ obj,
    const int* __restrict__ gkrem, const int* __restrict__ gcnt,
    int* __restrict__ sel, int* __restrict__ eqbuf){
  const int il=blockIdx.x, img=il/5, lvl=il%5;
  const int n=c_n[lvl], k=c_k[lvl];
  const float* o=obj+(size_t)img*TT+c_off[lvl];
  int* s=sel+img*KTOT+c_pos[lvl];
  __shared__ unsigned long long skey[1024];
  if(k<n){
    const int krem=gkrem[il];
    if(krem>0 && threadIdx.x==0){
      int cgt=gcnt[il*2];
      int ceq=min(gcnt[il*2+1],2048);
      int* eq=eqbuf+il*2048;
      for(int r2=0;r2<krem;r2++){
        int mn=0x7fffffff,mi=0;
        for(int j=0;j<ceq;j++) if(eq[j]<mn){mn=eq[j];mi=j;}
        s[cgt+r2]=mn; eq[mi]=0x7fffffff;
      }
    }
    __syncthreads();
  }
  for(int i=threadIdx.x;i<k;i+=256){
    int idx=s[i];
    skey[i]=((unsigned long long)fkey(o[idx])<<32)|(unsigned)(~(unsigned)idx);
  }
  __syncthreads();
  for(int i=threadIdx.x;i<k;i+=256){
    unsigned long long mk=skey[i];
    int rank=0;
    for(int j=0;j<k;j++) rank+=(skey[j]>mk)?1:0;
    int idx=(int)(~(unsigned)(mk&0xFFFFFFFFu));
    s[rank]=idx+c_off[lvl];
  }
}

// ---------------- K2a: decode+clip+score, build global sort keys, image max ----
__global__ __launch_bounds__(256) void k_decode(const float* __restrict__ obj,
    const float* __restrict__ del, const float* __restrict__ anc,
    const int* __restrict__ sel, float* __restrict__ pbox, float* __restrict__ pscore,
    int* __restrict__ plvl, unsigned long long* __restrict__ gkey,
    float* __restrict__ gmax){
  const int img=blockIdx.x;
  __shared__ float smax[256];
  const float BCLIP=(float)4.135166556742356;  // log(1000/16)
  float lm=0.f;
  for(int pos=threadIdx.x;pos<KTOT;pos+=256){
    int lvl = pos<1000?0:pos<2000?1:pos<3000?2:pos<4000?3:4;
    int tdx = sel[img*KTOT+pos];
    float logit = obj[(size_t)img*TT+tdx];
    const float* a=anc+4*(size_t)tdx;
    const float* d=del+((size_t)img*TT+tdx)*4;
    float w=a[2]-a[0], h=a[3]-a[1];
    float cx=a[0]+0.5f*w, cy=a[1]+0.5f*h;
    float dw=fminf(d[2],BCLIP), dh=fminf(d[3],BCLIP);
    float pcx=d[0]*w+cx, pcy=d[1]*h+cy;
    float pw=expf(dw)*w, ph=expf(dh)*h;
    float x1=pcx-0.5f*pw, y1=pcy-0.5f*ph;
    float x2=pcx+0.5f*pw, y2=pcy+0.5f*ph;
    x1=fminf(fmaxf(x1,0.f),800.f); y1=fminf(fmaxf(y1,0.f),800.f);
    x2=fminf(fmaxf(x2,0.f),800.f); y2=fminf(fmaxf(y2,0.f),800.f);
    int valid=(x2-x1>=1e-3f)&&(y2-y1>=1e-3f);
    float sc=1.f/(1.f+expf(-logit));
    float sv=valid? sc : -INFINITY;
    gkey[img*KTOT+pos]=((unsigned long long)fkey(sv)<<32)|(unsigned)(KTOT-1-pos);
    float* pb=pbox+((size_t)img*KTOT+pos)*4;
    pb[0]=x1; pb[1]=y1; pb[2]=x2; pb[3]=y2;
    pscore[img*KTOT+pos]=sc;
    plvl[img*KTOT+pos]=lvl|(valid?0:256);
    lm=fmaxf(lm,fmaxf(fmaxf(x1,y1),fmaxf(x2,y2)));
  }
  smax[threadIdx.x]=lm; __syncthreads();
  for(int st=128;st>0;st>>=1){
    if(threadIdx.x<st) smax[threadIdx.x]=fmaxf(smax[threadIdx.x],smax[threadIdx.x+st]);
    __syncthreads();
  }
  if(threadIdx.x==0) gmax[img]=smax[0];
}

// ---------------- K2b: global rank sort (score desc, pos asc) + scatter -------
__global__ __launch_bounds__(256) void k_rank(const unsigned long long* __restrict__ gkey,
    const float* __restrict__ pbox, const float* __restrict__ pscore,
    const int* __restrict__ plvl,
    float* __restrict__ sbox, float* __restrict__ sscore,
    int* __restrict__ slvl, int* __restrict__ ssupp){
  const int img=blockIdx.x/18, chunk=blockIdx.x%18;
  __shared__ unsigned long long key[KTOT];
  for(int i=threadIdx.x;i<KTOT;i+=256) key[i]=gkey[img*KTOT+i];
  __syncthreads();
  int pos=chunk*256+threadIdx.x;
  if(pos<KTOT){
    unsigned long long mk=key[pos];
    int rank=0;
    for(int j=0;j<KTOT;j++) rank+=(key[j]>mk)?1:0;
    const float* pb=pbox+((size_t)img*KTOT+pos)*4;
    float* sb=sbox+((size_t)img*KTOT+rank)*4;
    sb[0]=pb[0]; sb[1]=pb[1]; sb[2]=pb[2]; sb[3]=pb[3];
    sscore[img*KTOT+rank]=pscore[img*KTOT+pos];
    int lv=plvl[img*KTOT+pos];
    slvl[img*KTOT+rank]=lv&0xFF;
    ssupp[img*KTOT+rank]=(lv>>8)&1;   // invalid -> pre-suppressed
  }
}

// ---------------- K3a: per-(img,level) ordered candidate list (wave ballot) ---
__global__ __launch_bounds__(64) void k_list(const float* __restrict__ sbox,
    const int* __restrict__ slvl, const int* __restrict__ ssupp,
    const float* __restrict__ gmax,
    int* __restrict__ lists, int* __restrict__ mcnt,
    float4* __restrict__ nbox, float* __restrict__ narea){
  const int img=blockIdx.x/5, lvl=blockIdx.x%5;
  const int lane=threadIdx.x;
  int* list = lists + blockIdx.x*1024;
  int base=0;
  for(int t=0;t<KTOT;t+=64){
    int r=t+lane;
    bool pred = (r<KTOT) && (slvl[img*KTOT+r]==lvl) && (ssupp[img*KTOT+r]==0);
    unsigned long long b=__ballot(pred);
    int prefix=__popcll(b & ((1ull<<lane)-1ull));
    if(pred) list[base+prefix]=r;
    base+=__popcll(b);
  }
  if(lane==0) mcnt[blockIdx.x]=base;
  const int m=base;
  const float off=(float)lvl*(gmax[img]+1.0f);   // replicate ref offset math exactly
  for(int i=lane;i<m;i+=64){
    int r=list[i];
    const float* bx=sbox+((size_t)img*KTOT+r)*4;
    float a0=bx[0]+off, a1=bx[1]+off, a2=bx[2]+off, a3=bx[3]+off;
    nbox[blockIdx.x*1024+i]=make_float4(a0,a1,a2,a3);
    narea[blockIdx.x*1024+i]=(a2-a0)*(a3-a1);
  }
}

// ---------------- K3b: pairwise suppression bitmasks, 1 word/thread ------------
// grid (40, 64): blockIdx.y = rowchunk(0..3)*16 + word(0..15). Block covers rows
// [rc*256, rc*256+256) x one 64-bit mask word. 2560 blocks -> latency hidden.
__global__ __launch_bounds__(256) void k_mask(const float4* __restrict__ nbox,
    const float* __restrict__ narea, const int* __restrict__ mcnt,
    unsigned long long* __restrict__ mask){
  const int il=blockIdx.x;
  const int rc=blockIdx.y>>4, w=blockIdx.y&15;
  const int m=mcnt[il];
  const int r0=rc*256;
  if(r0>=m) return;
  const int i=r0+threadIdx.x;
  const int wlast=(m+63)>>6;
  __shared__ float4 sb[64];
  __shared__ float  sa[64];
  unsigned long long bits=0ull;
  const bool block_active = (w>=rc*4) && (w<wlast);   // rc*4 == min wi in block
  if(block_active){
    const int jend=min(64, m-w*64);
    if(threadIdx.x<64 && threadIdx.x<jend){
      sb[threadIdx.x]=nbox[il*1024+w*64+threadIdx.x];
      sa[threadIdx.x]=narea[il*1024+w*64+threadIdx.x];
    }
    __syncthreads();
    const int wi=i>>6;
    if(i<m && w>=wi){
      const float4 bi=nbox[il*1024+i];
      const float  ai=narea[il*1024+i];
      for(int jj=0;jj<jend;++jj){
        const float4 bj=sb[jj];                 // LDS broadcast
        float ltx=fmaxf(bi.x,bj.x), lty=fmaxf(bi.y,bj.y);
        float rbx=fminf(bi.z,bj.z), rby=fminf(bi.w,bj.w);
        float wx=fmaxf(rbx-ltx,0.f), wy=fmaxf(rby-lty,0.f);
        float inter=wx*wy;
        float iou=inter/((ai+sa[jj])-inter);
        bits |= (iou>0.7f)? (1ull<<jj) : 0ull;
      }
      if(w==wi){ int b=i&63; bits &= ~((2ull<<b)-1ull); }  // keep only j>i
    }
  }
  if(i<m) mask[((size_t)il*1024+i)*16+w]=bits;
}

// ---------------- K3c: greedy reduce; lane-local decisions, 1 shfl / 8 elems --
__global__ __launch_bounds__(64) void k_reduce(const unsigned long long* __restrict__ mask,
    const int* __restrict__ mcnt, const int* __restrict__ lists,
    int* __restrict__ ssupp){
  const int il=blockIdx.x, img=il/5;
  const int m=mcnt[il];
  const int lane=threadIdx.x;
  const unsigned long long* M = mask + (size_t)il*1024*16;
  const bool ld = lane<16;
  unsigned long long remv=0ull;
  unsigned long long c0,c1,c2,c3,c4,c5,c6,c7;
  unsigned long long n0,n1,n2,n3,n4,n5,n6,n7;
#define LD(r,b) ((ld && ((b)+(r))<m) ? M[(size_t)((b)+(r))*16+lane] : 0ull)
  c0=LD(0,0); c1=LD(1,0); c2=LD(2,0); c3=LD(3,0);
  c4=LD(4,0); c5=LD(5,0); c6=LD(6,0); c7=LD(7,0);
  for(int g=0;;++g){
    const int nb=(g+1)*8;
    n0=LD(0,nb); n1=LD(1,nb); n2=LD(2,nb); n3=LD(3,nb);
    n4=LD(4,nb); n5=LD(5,nb); n6=LD(6,nb); n7=LD(7,nb);
    const int base=g*8;
    const int w=base>>6;
    const int bb=base&63;
    unsigned t8=(unsigned)(remv>>bb);
    unsigned am=0u;
#define DEC(r,cr) { unsigned alive=1u^((t8>>(r))&1u); am|=alive<<(r); \
                    if(alive) t8|=(unsigned)((cr)>>bb); }
    DEC(0,c0) DEC(1,c1) DEC(2,c2) DEC(3,c3)
    DEC(4,c4) DEC(5,c5) DEC(6,c6) DEC(7,c7)
#undef DEC
    const int rem=m-base;
    unsigned vm=(rem>=8)?0xffu:((rem<=0)?0u:((1u<<rem)-1u));
    am&=vm;
    unsigned am_w=(unsigned)__shfl((int)am, w);
    if(am_w&1u)   remv|=c0;
    if(am_w&2u)   remv|=c1;
    if(am_w&4u)   remv|=c2;
    if(am_w&8u)   remv|=c3;
    if(am_w&16u)  remv|=c4;
    if(am_w&32u)  remv|=c5;
    if(am_w&64u)  remv|=c6;
    if(am_w&128u) remv|=c7;
    if(nb>=m) break;
    c0=n0; c1=n1; c2=n2; c3=n3; c4=n4; c5=n5; c6=n6; c7=n7;
  }
#undef LD
  const int* list = lists + il*1024;
  for(int t=0;t<m;t+=64){
    int i=t+lane;
    unsigned long long word=__shfl(remv, (i<m? i:0)>>6);
    if(i<m && ((word>>(i&63))&1ull)) ssupp[img*KTOT+list[i]]=1;
  }
}

// ---------------- K4: compact first 1000 survivors per image ------------------
__global__ __launch_bounds__(256) void k_out(const float* __restrict__ sbox,
    const float* __restrict__ sscore, const int* __restrict__ ssupp,
    float* __restrict__ out){
  const int img=blockIdx.x;
  __shared__ unsigned short list[POST];
  __shared__ int s_c;
  if(threadIdx.x<64){
    int base=0;
    for(int t=0;t<KTOT && base<POST;t+=64){
      int r=t+threadIdx.x;
      bool pred = (r<KTOT) && (ssupp[img*KTOT+r]==0);
      unsigned long long b=__ballot(pred);
      int pre=__popcll(b & ((1ull<<threadIdx.x)-1ull));
      if(pred && base+pre<POST) list[base+pre]=(unsigned short)r;
      base+=__popcll(b);
    }
    if(threadIdx.x==0) s_c=min(base,POST);
  }
  __syncthreads();
  const int c=s_c;
  for(int o=threadIdx.x;o<POST;o+=256){
    float* row=out+((size_t)img*POST+o)*5;
    if(o<c){
      int r=list[o];
      const float* b=sbox+((size_t)img*KTOT+r)*4;
      row[0]=b[0]; row[1]=b[1]; row[2]=b[2]; row[3]=b[3];
      row[4]=sscore[img*KTOT+r];
    } else {
      row[0]=0.f; row[1]=0.f; row[2]=0.f; row[3]=0.f; row[4]=0.f;
    }
  }
}

extern "C" void kernel_launch(void* const* d_in, const int* in_sizes, int n_in,
                              void* d_out, int out_size, void* d_ws, size_t ws_size,
                              hipStream_t stream){
  const float* obj=(const float*)d_in[0];
  const float* del=(const float*)d_in[1];
  const float* anc=(const float*)d_in[2];
  float* out=(float*)d_out;

  char* w=(char*)d_ws;
  size_t off=0;
  auto alloc=[&](size_t bytes)->void*{
    void* p=w+off; off+=(bytes+255)&~(size_t)255; return p;
  };
  int*  sel    =(int*)  alloc(sizeof(int)*NIMG*KTOT);
  float* pbox  =(float*)alloc(sizeof(float)*NIMG*KTOT*4);
  float* pscore=(float*)alloc(sizeof(float)*NIMG*KTOT);
  int*  plvl   =(int*)  alloc(sizeof(int)*NIMG*KTOT);
  unsigned long long* gkey=(unsigned long long*)alloc(sizeof(unsigned long long)*NIMG*KTOT);
  float* sbox  =(float*)alloc(sizeof(float)*NIMG*KTOT*4);
  float* sscore=(float*)alloc(sizeof(float)*NIMG*KTOT);
  int*  slvl   =(int*)  alloc(sizeof(int)*NIMG*KTOT);
  int*  ssupp  =(int*)  alloc(sizeof(int)*NIMG*KTOT);
  float* gmax  =(float*)alloc(sizeof(float)*NIMG);
  int*  eqbuf  =(int*)  alloc(sizeof(int)*40*2048);
  int*  lists  =(int*)  alloc(sizeof(int)*40*1024);
  int*  mcnt   =(int*)  alloc(sizeof(int)*40);
  float4* nbox =(float4*)alloc(sizeof(float4)*40*1024);
  float* narea =(float*)alloc(sizeof(float)*40*1024);
  unsigned long long* mask=(unsigned long long*)alloc(sizeof(unsigned long long)*40*1024*16);
  unsigned* ghist=(unsigned*)alloc(sizeof(unsigned)*40*2048);
  unsigned* gpref=(unsigned*)alloc(sizeof(unsigned)*40);
  int*  gkrem  =(int*)  alloc(sizeof(int)*40);
  int*  gcnt   =(int*)  alloc(sizeof(int)*80);

  hipLaunchKernelGGL(k_zero,    dim3((40*2048+255)/256), dim3(256), 0, stream, ghist);
  hipLaunchKernelGGL(k_hist<0>, dim3(40,NSUB), dim3(256), 0, stream, obj, gpref, ghist);
  hipLaunchKernelGGL(k_scan<0>, dim3(40), dim3(256), 0, stream, ghist, gpref, gkrem, gcnt);
  hipLaunchKernelGGL(k_hist<1>, dim3(40,NSUB), dim3(256), 0, stream, obj, gpref, ghist);
  hipLaunchKernelGGL(k_scan<1>, dim3(40), dim3(256), 0, stream, ghist, gpref, gkrem, gcnt);
  hipLaunchKernelGGL(k_hist<2>, dim3(40,NSUB), dim3(256), 0, stream, obj, gpref, ghist);
  hipLaunchKernelGGL(k_scan<2>, dim3(40), dim3(256), 0, stream, ghist, gpref, gkrem, gcnt);
  hipLaunchKernelGGL(k_sel,    dim3(40,NSUB), dim3(256), 0, stream, obj, gpref, gkrem,
                     gcnt, sel, eqbuf);
  hipLaunchKernelGGL(k_sort,   dim3(40), dim3(256), 0, stream, obj, gkrem, gcnt, sel, eqbuf);
  hipLaunchKernelGGL(k_decode, dim3(NIMG), dim3(256), 0, stream, obj, del, anc, sel,
                     pbox, pscore, plvl, gkey, gmax);
  hipLaunchKernelGGL(k_rank,   dim3(NIMG*18), dim3(256), 0, stream, gkey, pbox, pscore,
                     plvl, sbox, sscore, slvl, ssupp);
  hipLaunchKernelGGL(k_list,   dim3(40), dim3(64), 0, stream, sbox, slvl, ssupp, gmax,
                     lists, mcnt, nbox, narea);
  hipLaunchKernelGGL(k_mask,   dim3(40,64), dim3(256), 0, stream, nbox, narea, mcnt, mask);
  hipLaunchKernelGGL(k_reduce, dim3(40), dim3(64), 0, stream, mask, mcnt, lists, ssupp);
  hipLaunchKernelGGL(k_out,    dim3(NIMG), dim3(256), 0, stream, sbox, sscore, ssupp, out);
}

// Round 6
// 330.684 us; speedup vs baseline: 4.6670x; 1.2344x over previous
//
#include <hip/hip_runtime.h>
#include <math.h>

#define NIMG 8
#define TT   159882
#define KTOT 4507
#define POST 1000
#define NSUB 32

__constant__ int c_n[5]   = {120000,30000,7500,1875,507};
__constant__ int c_off[5] = {0,120000,150000,157500,159375};
__constant__ int c_k[5]   = {1000,1000,1000,1000,507};
__constant__ int c_pos[5] = {0,1000,2000,3000,4000};

__device__ __forceinline__ unsigned fkey(float f){
  unsigned u=__float_as_uint(f);
  return (u&0x80000000u)? ~u : (u|0x80000000u);
}

// ---------------- K0: zero global histograms + rank array ---------------------
__global__ __launch_bounds__(256) void k_zero(unsigned* __restrict__ ghist,
                                              int* __restrict__ grank){
  int i=blockIdx.x*256+threadIdx.x;
  if(i<40*2048) ghist[i]=0u;
  int j=i-40*2048;
  if(j>=0 && j<NIMG*KTOT) grank[j]=0;
}

// ---------------- K1a: distributed radix histogram (one round) ----------------
template<int RND>
__global__ __launch_bounds__(256) void k_hist(const float* __restrict__ obj,
    const unsigned* __restrict__ gpref, unsigned* __restrict__ ghist){
  constexpr int sh=(RND==0)?21:(RND==1)?10:0;
  constexpr int nb=(RND==2)?1024:2048;
  constexpr unsigned msk=(unsigned)(nb-1);
  const int il=blockIdx.x, sub=blockIdx.y;
  const int img=il/5, lvl=il%5;
  const int n=c_n[lvl], k=c_k[lvl];
  if(k>=n) return;
  const int chunk=(n+NSUB-1)/NSUB;
  const int start=sub*chunk, end=min(start+chunk,n);
  if(start>=end) return;
  const float* o=obj+(size_t)img*TT+c_off[lvl];
  __shared__ unsigned hist[2048];
  const unsigned prefix=(RND==0)?0u:gpref[il];
  for(int i=threadIdx.x;i<nb;i+=256) hist[i]=0u;
  __syncthreads();
  for(int i=start+threadIdx.x;i<end;i+=256){
    unsigned key=fkey(o[i]);
    if(RND==0){
      atomicAdd(&hist[(key>>sh)&msk],1u);
    } else {
      constexpr unsigned hiMask=0xFFFFFFFFu<<((RND==1)?21:10);
      if((key&hiMask)==prefix) atomicAdd(&hist[(key>>sh)&msk],1u);
    }
  }
  __syncthreads();
  for(int b=threadIdx.x;b<nb;b+=256){
    unsigned v=hist[b];
    if(v) atomicAdd(&ghist[il*2048+b],v);
  }
}

// ---------------- K1b: pick bucket via register suffix-sum + LDS tree ---------
template<int RND>
__global__ __launch_bounds__(256) void k_scan(unsigned* __restrict__ ghist,
    unsigned* __restrict__ gpref, int* __restrict__ gkrem,
    int* __restrict__ gcnt){
  constexpr int sh=(RND==0)?21:(RND==1)?10:0;
  constexpr int nb=(RND==2)?1024:2048;
  constexpr int C=nb/256;
  const int il=blockIdx.x, lvl=il%5;
  const int n=c_n[lvl], k=c_k[lvl];
  const int t=threadIdx.x;
  __shared__ unsigned tot[256];
  if(k>=n){
    if(RND==2 && t==0){ gpref[il]=0u; gkrem[il]=0; gcnt[il*2]=0; gcnt[il*2+1]=0; }
    return;
  }
  const int kr=(RND==0)?k:gkrem[il];
  unsigned v[C];
#pragma unroll
  for(int i=0;i<C;i++) v[i]=ghist[il*2048+t*C+i];
#pragma unroll
  for(int i=C-2;i>=0;i--) v[i]+=v[i+1];          // local suffix sum (registers)
  tot[t]=v[0];
  __syncthreads();
#pragma unroll
  for(int d=1;d<256;d<<=1){                       // inclusive suffix scan of totals
    unsigned add=(t+d<256)?tot[t+d]:0u;
    __syncthreads();
    tot[t]+=add;
    __syncthreads();
  }
  unsigned tail=(t<255)?tot[t+1]:0u;
#pragma unroll
  for(int i=0;i<C;i++){
    unsigned suf=v[i]+tail;
    unsigned sufn=((i<C-1)?v[i+1]:0u)+tail;
    if(suf>=(unsigned)kr && sufn<(unsigned)kr){
      unsigned prevPref=(RND==0)?0u:gpref[il];
      gpref[il]=prevPref|((unsigned)(t*C+i)<<sh);
      gkrem[il]=kr-(int)sufn;
    }
  }
  for(int b=t;b<2048;b+=256) ghist[il*2048+b]=0u; // ready for next round/replay
  if(RND==2 && t==0){ gcnt[il*2]=0; gcnt[il*2+1]=0; }
}

// ---------------- K1c: distributed selection against final threshold ---------
__global__ __launch_bounds__(256) void k_sel(const float* __restrict__ obj,
    const unsigned* __restrict__ gpref, const int* __restrict__ gkrem,
    int* __restrict__ gcnt, int* __restrict__ sel, int* __restrict__ eqbuf){
  const int il=blockIdx.x, sub=blockIdx.y;
  const int img=il/5, lvl=il%5;
  const int n=c_n[lvl], k=c_k[lvl];
  const int chunk=(n+NSUB-1)/NSUB;
  const int start=sub*chunk, end=min(start+chunk,n);
  if(start>=end) return;
  int* s=sel+img*KTOT+c_pos[lvl];
  if(k>=n){
    for(int i=start+threadIdx.x;i<end;i+=256) s[i]=i;
    return;
  }
  const float* o=obj+(size_t)img*TT+c_off[lvl];
  const unsigned t=gpref[il];
  const int krem=gkrem[il];
  for(int i=start+threadIdx.x;i<end;i+=256){
    unsigned key=fkey(o[i]);
    if(key>t){ s[atomicAdd(&gcnt[il*2],1)]=i; }
    else if(key==t && krem>0){ int p=atomicAdd(&gcnt[il*2+1],1); if(p<2048) eqbuf[il*2048+p]=i; }
  }
}

// ---------------- K1d: eq-tiebreak picks + level rank sort --------------------
__global__ __launch_bounds__(256) void k_sort(const float* __restrict__ obj,
    const int* __restrict__ gkrem, const int* __restrict__ gcnt,
    int* __restrict__ sel, int* __restrict__ eqbuf){
  const int il=blockIdx.x, img=il/5, lvl=il%5;
  const int n=c_n[lvl], k=c_k[lvl];
  const float* o=obj+(size_t)img*TT+c_off[lvl];
  int* s=sel+img*KTOT+c_pos[lvl];
  __shared__ unsigned long long skey[1024];
  if(k<n){
    const int krem=gkrem[il];
    if(krem>0 && threadIdx.x==0){
      int cgt=gcnt[il*2];
      int ceq=min(gcnt[il*2+1],2048);
      int* eq=eqbuf+il*2048;
      for(int r2=0;r2<krem;r2++){
        int mn=0x7fffffff,mi=0;
        for(int j=0;j<ceq;j++) if(eq[j]<mn){mn=eq[j];mi=j;}
        s[cgt+r2]=mn; eq[mi]=0x7fffffff;
      }
    }
    __syncthreads();
  }
  for(int i=threadIdx.x;i<k;i+=256){
    int idx=s[i];
    skey[i]=((unsigned long long)fkey(o[idx])<<32)|(unsigned)(~(unsigned)idx);
  }
  __syncthreads();
  for(int i=threadIdx.x;i<k;i+=256){
    unsigned long long mk=skey[i];
    int rank=0;
    for(int j=0;j<k;j++) rank+=(skey[j]>mk)?1:0;
    int idx=(int)(~(unsigned)(mk&0xFFFFFFFFu));
    s[rank]=idx+c_off[lvl];
  }
}

// ---------------- K2a: decode+clip+score, build global sort keys, image max ----
__global__ __launch_bounds__(256) void k_decode(const float* __restrict__ obj,
    const float* __restrict__ del, const float* __restrict__ anc,
    const int* __restrict__ sel, float* __restrict__ pbox, float* __restrict__ pscore,
    int* __restrict__ plvl, unsigned long long* __restrict__ gkey,
    float* __restrict__ gmax){
  const int img=blockIdx.x;
  __shared__ float smax[256];
  const float BCLIP=(float)4.135166556742356;  // log(1000/16)
  float lm=0.f;
  for(int pos=threadIdx.x;pos<KTOT;pos+=256){
    int lvl = pos<1000?0:pos<2000?1:pos<3000?2:pos<4000?3:4;
    int tdx = sel[img*KTOT+pos];
    float logit = obj[(size_t)img*TT+tdx];
    const float* a=anc+4*(size_t)tdx;
    const float* d=del+((size_t)img*TT+tdx)*4;
    float w=a[2]-a[0], h=a[3]-a[1];
    float cx=a[0]+0.5f*w, cy=a[1]+0.5f*h;
    float dw=fminf(d[2],BCLIP), dh=fminf(d[3],BCLIP);
    float pcx=d[0]*w+cx, pcy=d[1]*h+cy;
    float pw=expf(dw)*w, ph=expf(dh)*h;
    float x1=pcx-0.5f*pw, y1=pcy-0.5f*ph;
    float x2=pcx+0.5f*pw, y2=pcy+0.5f*ph;
    x1=fminf(fmaxf(x1,0.f),800.f); y1=fminf(fmaxf(y1,0.f),800.f);
    x2=fminf(fmaxf(x2,0.f),800.f); y2=fminf(fmaxf(y2,0.f),800.f);
    int valid=(x2-x1>=1e-3f)&&(y2-y1>=1e-3f);
    float sc=1.f/(1.f+expf(-logit));
    float sv=valid? sc : -INFINITY;
    gkey[img*KTOT+pos]=((unsigned long long)fkey(sv)<<32)|(unsigned)(KTOT-1-pos);
    float* pb=pbox+((size_t)img*KTOT+pos)*4;
    pb[0]=x1; pb[1]=y1; pb[2]=x2; pb[3]=y2;
    pscore[img*KTOT+pos]=sc;
    plvl[img*KTOT+pos]=lvl|(valid?0:256);
    lm=fmaxf(lm,fmaxf(fmaxf(x1,y1),fmaxf(x2,y2)));
  }
  smax[threadIdx.x]=lm; __syncthreads();
  for(int st=128;st>0;st>>=1){
    if(threadIdx.x<st) smax[threadIdx.x]=fmaxf(smax[threadIdx.x],smax[threadIdx.x+st]);
    __syncthreads();
  }
  if(threadIdx.x==0) gmax[img]=smax[0];
}

// ---------------- K2b: partial rank counts, 256x256 tiles ---------------------
// grid (8, 18, 18): img x ichunk x jchunk. 2592 blocks -> latency hidden.
__global__ __launch_bounds__(256) void k_rankp(const unsigned long long* __restrict__ gkey,
    int* __restrict__ grank){
  const int img=blockIdx.x, ic=blockIdx.y, jc=blockIdx.z;
  __shared__ unsigned long long sk[256];
  const int jbase=jc*256;
  const int jend=min(256, KTOT-jbase);
  const int i=ic*256+threadIdx.x;
  if(threadIdx.x<jend) sk[threadIdx.x]=gkey[img*KTOT+jbase+threadIdx.x];
  __syncthreads();
  if(i>=KTOT) return;
  const unsigned long long mk=gkey[img*KTOT+i];
  int r=0;
  #pragma unroll 4
  for(int j=0;j<jend;j++) r+=(sk[j]>mk)?1:0;
  if(r) atomicAdd(&grank[img*KTOT+i], r);
}

// ---------------- K2c: scatter by rank ---------------------------------------
__global__ __launch_bounds__(256) void k_scatter(const int* __restrict__ grank,
    const float4* __restrict__ pbox, const float* __restrict__ pscore,
    const int* __restrict__ plvl,
    float4* __restrict__ sbox, float* __restrict__ sscore,
    int* __restrict__ slvl, int* __restrict__ ssupp){
  const int img=blockIdx.x/18, chunk=blockIdx.x%18;
  const int pos=chunk*256+threadIdx.x;
  if(pos>=KTOT) return;
  const int rank=grank[img*KTOT+pos];
  sbox[(size_t)img*KTOT+rank]=pbox[(size_t)img*KTOT+pos];
  sscore[img*KTOT+rank]=pscore[img*KTOT+pos];
  int lv=plvl[img*KTOT+pos];
  slvl[img*KTOT+rank]=lv&0xFF;
  ssupp[img*KTOT+rank]=(lv>>8)&1;   // invalid -> pre-suppressed
}

// ---------------- K3a: per-(img,level) ordered candidate list (wave ballot) ---
__global__ __launch_bounds__(64) void k_list(const float* __restrict__ sbox,
    const int* __restrict__ slvl, const int* __restrict__ ssupp,
    const float* __restrict__ gmax,
    int* __restrict__ lists, int* __restrict__ mcnt,
    float4* __restrict__ nbox, float* __restrict__ narea){
  const int img=blockIdx.x/5, lvl=blockIdx.x%5;
  const int lane=threadIdx.x;
  int* list = lists + blockIdx.x*1024;
  int base=0;
  for(int t=0;t<KTOT;t+=64){
    int r=t+lane;
    bool pred = (r<KTOT) && (slvl[img*KTOT+r]==lvl) && (ssupp[img*KTOT+r]==0);
    unsigned long long b=__ballot(pred);
    int prefix=__popcll(b & ((1ull<<lane)-1ull));
    if(pred) list[base+prefix]=r;
    base+=__popcll(b);
  }
  if(lane==0) mcnt[blockIdx.x]=base;
  const int m=base;
  const float off=(float)lvl*(gmax[img]+1.0f);   // replicate ref offset math exactly
  for(int i=lane;i<m;i+=64){
    int r=list[i];
    const float* bx=sbox+((size_t)img*KTOT+r)*4;
    float a0=bx[0]+off, a1=bx[1]+off, a2=bx[2]+off, a3=bx[3]+off;
    nbox[blockIdx.x*1024+i]=make_float4(a0,a1,a2,a3);
    narea[blockIdx.x*1024+i]=(a2-a0)*(a3-a1);
  }
}

// ---------------- K3b: pairwise suppression bitmasks, 1 word/thread ------------
__global__ __launch_bounds__(256) void k_mask(const float4* __restrict__ nbox,
    const float* __restrict__ narea, const int* __restrict__ mcnt,
    unsigned long long* __restrict__ mask){
  const int il=blockIdx.x;
  const int rc=blockIdx.y>>4, w=blockIdx.y&15;
  const int m=mcnt[il];
  const int r0=rc*256;
  if(r0>=m) return;
  const int i=r0+threadIdx.x;
  const int wlast=(m+63)>>6;
  __shared__ float4 sb[64];
  __shared__ float  sa[64];
  unsigned long long bits=0ull;
  const bool block_active = (w>=rc*4) && (w<wlast);   // rc*4 == min wi in block
  if(block_active){
    const int jend=min(64, m-w*64);
    if(threadIdx.x<64 && threadIdx.x<jend){
      sb[threadIdx.x]=nbox[il*1024+w*64+threadIdx.x];
      sa[threadIdx.x]=narea[il*1024+w*64+threadIdx.x];
    }
    __syncthreads();
    const int wi=i>>6;
    if(i<m && w>=wi){
      const float4 bi=nbox[il*1024+i];
      const float  ai=narea[il*1024+i];
      for(int jj=0;jj<jend;++jj){
        const float4 bj=sb[jj];                 // LDS broadcast
        float ltx=fmaxf(bi.x,bj.x), lty=fmaxf(bi.y,bj.y);
        float rbx=fminf(bi.z,bj.z), rby=fminf(bi.w,bj.w);
        float wx=fmaxf(rbx-ltx,0.f), wy=fmaxf(rby-lty,0.f);
        float inter=wx*wy;
        float iou=inter/((ai+sa[jj])-inter);
        bits |= (iou>0.7f)? (1ull<<jj) : 0ull;
      }
      if(w==wi){ int b=i&63; bits &= ~((2ull<<b)-1ull); }  // keep only j>i
    }
  }
  if(i<m) mask[((size_t)il*1024+i)*16+w]=bits;
}

// ---------------- K3c: greedy reduce; lane-local decisions, 1 shfl / 8 elems --
__global__ __launch_bounds__(64) void k_reduce(const unsigned long long* __restrict__ mask,
    const int* __restrict__ mcnt, const int* __restrict__ lists,
    int* __restrict__ ssupp){
  const int il=blockIdx.x, img=il/5;
  const int m=mcnt[il];
  const int lane=threadIdx.x;
  const unsigned long long* M = mask + (size_t)il*1024*16;
  const bool ld = lane<16;
  unsigned long long remv=0ull;
  unsigned long long c0,c1,c2,c3,c4,c5,c6,c7;
  unsigned long long n0,n1,n2,n3,n4,n5,n6,n7;
#define LD(r,b) ((ld && ((b)+(r))<m) ? M[(size_t)((b)+(r))*16+lane] : 0ull)
  c0=LD(0,0); c1=LD(1,0); c2=LD(2,0); c3=LD(3,0);
  c4=LD(4,0); c5=LD(5,0); c6=LD(6,0); c7=LD(7,0);
  for(int g=0;;++g){
    const int nb=(g+1)*8;
    n0=LD(0,nb); n1=LD(1,nb); n2=LD(2,nb); n3=LD(3,nb);
    n4=LD(4,nb); n5=LD(5,nb); n6=LD(6,nb); n7=LD(7,nb);
    const int base=g*8;
    const int w=base>>6;
    const int bb=base&63;
    unsigned t8=(unsigned)(remv>>bb);
    unsigned am=0u;
#define DEC(r,cr) { unsigned alive=1u^((t8>>(r))&1u); am|=alive<<(r); \
                    if(alive) t8|=(unsigned)((cr)>>bb); }
    DEC(0,c0) DEC(1,c1) DEC(2,c2) DEC(3,c3)
    DEC(4,c4) DEC(5,c5) DEC(6,c6) DEC(7,c7)
#undef DEC
    const int rem=m-base;
    unsigned vm=(rem>=8)?0xffu:((rem<=0)?0u:((1u<<rem)-1u));
    am&=vm;
    unsigned am_w=(unsigned)__shfl((int)am, w);
    if(am_w&1u)   remv|=c0;
    if(am_w&2u)   remv|=c1;
    if(am_w&4u)   remv|=c2;
    if(am_w&8u)   remv|=c3;
    if(am_w&16u)  remv|=c4;
    if(am_w&32u)  remv|=c5;
    if(am_w&64u)  remv|=c6;
    if(am_w&128u) remv|=c7;
    if(nb>=m) break;
    c0=n0; c1=n1; c2=n2; c3=n3; c4=n4; c5=n5; c6=n6; c7=n7;
  }
#undef LD
  const int* list = lists + il*1024;
  for(int t=0;t<m;t+=64){
    int i=t+lane;
    unsigned long long word=__shfl(remv, (i<m? i:0)>>6);
    if(i<m && ((word>>(i&63))&1ull)) ssupp[img*KTOT+list[i]]=1;
  }
}

// ---------------- K4: compact first 1000 survivors per image ------------------
__global__ __launch_bounds__(256) void k_out(const float* __restrict__ sbox,
    const float* __restrict__ sscore, const int* __restrict__ ssupp,
    float* __restrict__ out){
  const int img=blockIdx.x;
  __shared__ unsigned short list[POST];
  __shared__ int s_c;
  if(threadIdx.x<64){
    int base=0;
    for(int t=0;t<KTOT && base<POST;t+=64){
      int r=t+threadIdx.x;
      bool pred = (r<KTOT) && (ssupp[img*KTOT+r]==0);
      unsigned long long b=__ballot(pred);
      int pre=__popcll(b & ((1ull<<threadIdx.x)-1ull));
      if(pred && base+pre<POST) list[base+pre]=(unsigned short)r;
      base+=__popcll(b);
    }
    if(threadIdx.x==0) s_c=min(base,POST);
  }
  __syncthreads();
  const int c=s_c;
  for(int o=threadIdx.x;o<POST;o+=256){
    float* row=out+((size_t)img*POST+o)*5;
    if(o<c){
      int r=list[o];
      const float* b=sbox+((size_t)img*KTOT+r)*4;
      row[0]=b[0]; row[1]=b[1]; row[2]=b[2]; row[3]=b[3];
      row[4]=sscore[img*KTOT+r];
    } else {
      row[0]=0.f; row[1]=0.f; row[2]=0.f; row[3]=0.f; row[4]=0.f;
    }
  }
}

extern "C" void kernel_launch(void* const* d_in, const int* in_sizes, int n_in,
                              void* d_out, int out_size, void* d_ws, size_t ws_size,
                              hipStream_t stream){
  const float* obj=(const float*)d_in[0];
  const float* del=(const float*)d_in[1];
  const float* anc=(const float*)d_in[2];
  float* out=(float*)d_out;

  char* w=(char*)d_ws;
  size_t off=0;
  auto alloc=[&](size_t bytes)->void*{
    void* p=w+off; off+=(bytes+255)&~(size_t)255; return p;
  };
  int*  sel    =(int*)  alloc(sizeof(int)*NIMG*KTOT);
  float* pbox  =(float*)alloc(sizeof(float)*NIMG*KTOT*4);
  float* pscore=(float*)alloc(sizeof(float)*NIMG*KTOT);
  int*  plvl   =(int*)  alloc(sizeof(int)*NIMG*KTOT);
  unsigned long long* gkey=(unsigned long long*)alloc(sizeof(unsigned long long)*NIMG*KTOT);
  float* sbox  =(float*)alloc(sizeof(float)*NIMG*KTOT*4);
  float* sscore=(float*)alloc(sizeof(float)*NIMG*KTOT);
  int*  slvl   =(int*)  alloc(sizeof(int)*NIMG*KTOT);
  int*  ssupp  =(int*)  alloc(sizeof(int)*NIMG*KTOT);
  float* gmax  =(float*)alloc(sizeof(float)*NIMG);
  int*  eqbuf  =(int*)  alloc(sizeof(int)*40*2048);
  int*  lists  =(int*)  alloc(sizeof(int)*40*1024);
  int*  mcnt   =(int*)  alloc(sizeof(int)*40);
  float4* nbox =(float4*)alloc(sizeof(float4)*40*1024);
  float* narea =(float*)alloc(sizeof(float)*40*1024);
  unsigned long long* mask=(unsigned long long*)alloc(sizeof(unsigned long long)*40*1024*16);
  unsigned* ghist=(unsigned*)alloc(sizeof(unsigned)*40*2048);
  unsigned* gpref=(unsigned*)alloc(sizeof(unsigned)*40);
  int*  gkrem  =(int*)  alloc(sizeof(int)*40);
  int*  gcnt   =(int*)  alloc(sizeof(int)*80);
  int*  grank  =(int*)  alloc(sizeof(int)*NIMG*KTOT);

  hipLaunchKernelGGL(k_zero,    dim3((40*2048+NIMG*KTOT+255)/256), dim3(256), 0, stream,
                     ghist, grank);
  hipLaunchKernelGGL(k_hist<0>, dim3(40,NSUB), dim3(256), 0, stream, obj, gpref, ghist);
  hipLaunchKernelGGL(k_scan<0>, dim3(40), dim3(256), 0, stream, ghist, gpref, gkrem, gcnt);
  hipLaunchKernelGGL(k_hist<1>, dim3(40,NSUB), dim3(256), 0, stream, obj, gpref, ghist);
  hipLaunchKernelGGL(k_scan<1>, dim3(40), dim3(256), 0, stream, ghist, gpref, gkrem, gcnt);
  hipLaunchKernelGGL(k_hist<2>, dim3(40,NSUB), dim3(256), 0, stream, obj, gpref, ghist);
  hipLaunchKernelGGL(k_scan<2>, dim3(40), dim3(256), 0, stream, ghist, gpref, gkrem, gcnt);
  hipLaunchKernelGGL(k_sel,    dim3(40,NSUB), dim3(256), 0, stream, obj, gpref, gkrem,
                     gcnt, sel, eqbuf);
  hipLaunchKernelGGL(k_sort,   dim3(40), dim3(256), 0, stream, obj, gkrem, gcnt, sel, eqbuf);
  hipLaunchKernelGGL(k_decode, dim3(NIMG), dim3(256), 0, stream, obj, del, anc, sel,
                     pbox, pscore, plvl, gkey, gmax);
  hipLaunchKernelGGL(k_rankp,  dim3(NIMG,18,18), dim3(256), 0, stream, gkey, grank);
  hipLaunchKernelGGL(k_scatter,dim3(NIMG*18), dim3(256), 0, stream, grank,
                     (const float4*)pbox, pscore, plvl,
                     (float4*)sbox, sscore, slvl, ssupp);
  hipLaunchKernelGGL(k_list,   dim3(40), dim3(64), 0, stream, sbox, slvl, ssupp, gmax,
                     lists, mcnt, nbox, narea);
  hipLaunchKernelGGL(k_mask,   dim3(40,64), dim3(256), 0, stream, nbox, narea, mcnt, mask);
  hipLaunchKernelGGL(k_reduce, dim3(40), dim3(64), 0, stream, mask, mcnt, lists, ssupp);
  hipLaunchKernelGGL(k_out,    dim3(NIMG), dim3(256), 0, stream, sbox, sscore, ssupp, out);
}

// Round 7
// 319.216 us; speedup vs baseline: 4.8347x; 1.0359x over previous
//
#include <hip/hip_runtime.h>
#include <math.h>

#define NIMG 8
#define TT   159882
#define KTOT 4507
#define POST 1000
#define NSUB 32

__constant__ int c_n[5]   = {120000,30000,7500,1875,507};
__constant__ int c_off[5] = {0,120000,150000,157500,159375};
__constant__ int c_k[5]   = {1000,1000,1000,1000,507};
__constant__ int c_pos[5] = {0,1000,2000,3000,4000};

__device__ __forceinline__ unsigned fkey(float f){
  unsigned u=__float_as_uint(f);
  return (u&0x80000000u)? ~u : (u|0x80000000u);
}

// ---------------- K0: zero global histograms + rank array ---------------------
__global__ __launch_bounds__(256) void k_zero(unsigned* __restrict__ ghist,
                                              int* __restrict__ grank){
  int i=blockIdx.x*256+threadIdx.x;
  if(i<40*2048) ghist[i]=0u;
  int j=i-40*2048;
  if(j>=0 && j<NIMG*KTOT) grank[j]=0;
}

// ---------------- K1a: distributed radix histogram (one round) ----------------
template<int RND>
__global__ __launch_bounds__(256) void k_hist(const float* __restrict__ obj,
    const unsigned* __restrict__ gpref, unsigned* __restrict__ ghist){
  constexpr int sh=(RND==0)?21:(RND==1)?10:0;
  constexpr int nb=(RND==2)?1024:2048;
  constexpr unsigned msk=(unsigned)(nb-1);
  const int il=blockIdx.x, sub=blockIdx.y;
  const int img=il/5, lvl=il%5;
  const int n=c_n[lvl], k=c_k[lvl];
  if(k>=n) return;
  const int chunk=(n+NSUB-1)/NSUB;
  const int start=sub*chunk, end=min(start+chunk,n);
  if(start>=end) return;
  const float* o=obj+(size_t)img*TT+c_off[lvl];
  __shared__ unsigned hist[2048];
  const unsigned prefix=(RND==0)?0u:gpref[il];
  for(int i=threadIdx.x;i<nb;i+=256) hist[i]=0u;
  __syncthreads();
  for(int i=start+threadIdx.x;i<end;i+=256){
    unsigned key=fkey(o[i]);
    if(RND==0){
      atomicAdd(&hist[(key>>sh)&msk],1u);
    } else {
      constexpr unsigned hiMask=0xFFFFFFFFu<<((RND==1)?21:10);
      if((key&hiMask)==prefix) atomicAdd(&hist[(key>>sh)&msk],1u);
    }
  }
  __syncthreads();
  for(int b=threadIdx.x;b<nb;b+=256){
    unsigned v=hist[b];
    if(v) atomicAdd(&ghist[il*2048+b],v);
  }
}

// ---------------- K1b: pick bucket via register suffix-sum + LDS tree ---------
template<int RND>
__global__ __launch_bounds__(256) void k_scan(unsigned* __restrict__ ghist,
    unsigned* __restrict__ gpref, int* __restrict__ gkrem,
    int* __restrict__ gcnt){
  constexpr int sh=(RND==0)?21:(RND==1)?10:0;
  constexpr int nb=(RND==2)?1024:2048;
  constexpr int C=nb/256;
  const int il=blockIdx.x, lvl=il%5;
  const int n=c_n[lvl], k=c_k[lvl];
  const int t=threadIdx.x;
  __shared__ unsigned tot[256];
  if(k>=n){
    if(RND==2 && t==0){ gpref[il]=0u; gkrem[il]=0; gcnt[il*2]=0; gcnt[il*2+1]=0; }
    return;
  }
  const int kr=(RND==0)?k:gkrem[il];
  unsigned v[C];
#pragma unroll
  for(int i=0;i<C;i++) v[i]=ghist[il*2048+t*C+i];
#pragma unroll
  for(int i=C-2;i>=0;i--) v[i]+=v[i+1];          // local suffix sum (registers)
  tot[t]=v[0];
  __syncthreads();
#pragma unroll
  for(int d=1;d<256;d<<=1){                       // inclusive suffix scan of totals
    unsigned add=(t+d<256)?tot[t+d]:0u;
    __syncthreads();
    tot[t]+=add;
    __syncthreads();
  }
  unsigned tail=(t<255)?tot[t+1]:0u;
#pragma unroll
  for(int i=0;i<C;i++){
    unsigned suf=v[i]+tail;
    unsigned sufn=((i<C-1)?v[i+1]:0u)+tail;
    if(suf>=(unsigned)kr && sufn<(unsigned)kr){
      unsigned prevPref=(RND==0)?0u:gpref[il];
      gpref[il]=prevPref|((unsigned)(t*C+i)<<sh);
      gkrem[il]=kr-(int)sufn;
    }
  }
  for(int b=t;b<2048;b+=256) ghist[il*2048+b]=0u; // ready for next round/replay
  if(RND==2 && t==0){ gcnt[il*2]=0; gcnt[il*2+1]=0; }
}

// ---------------- K1c: distributed selection against final threshold ---------
__global__ __launch_bounds__(256) void k_sel(const float* __restrict__ obj,
    const unsigned* __restrict__ gpref, const int* __restrict__ gkrem,
    int* __restrict__ gcnt, int* __restrict__ sel, int* __restrict__ eqbuf){
  const int il=blockIdx.x, sub=blockIdx.y;
  const int img=il/5, lvl=il%5;
  const int n=c_n[lvl], k=c_k[lvl];
  const int chunk=(n+NSUB-1)/NSUB;
  const int start=sub*chunk, end=min(start+chunk,n);
  if(start>=end) return;
  int* s=sel+img*KTOT+c_pos[lvl];
  if(k>=n){
    for(int i=start+threadIdx.x;i<end;i+=256) s[i]=i;
    return;
  }
  const float* o=obj+(size_t)img*TT+c_off[lvl];
  const unsigned t=gpref[il];
  const int krem=gkrem[il];
  for(int i=start+threadIdx.x;i<end;i+=256){
    unsigned key=fkey(o[i]);
    if(key>t){ s[atomicAdd(&gcnt[il*2],1)]=i; }
    else if(key==t && krem>0){ int p=atomicAdd(&gcnt[il*2+1],1); if(p<2048) eqbuf[il*2048+p]=i; }
  }
}

// ---------------- K1d: eq-tiebreak picks + level rank sort --------------------
__global__ __launch_bounds__(256) void k_sort(const float* __restrict__ obj,
    const int* __restrict__ gkrem, const int* __restrict__ gcnt,
    int* __restrict__ sel, int* __restrict__ eqbuf){
  const int il=blockIdx.x, img=il/5, lvl=il%5;
  const int n=c_n[lvl], k=c_k[lvl];
  const float* o=obj+(size_t)img*TT+c_off[lvl];
  int* s=sel+img*KTOT+c_pos[lvl];
  __shared__ unsigned long long skey[1024];
  if(k<n){
    const int krem=gkrem[il];
    if(krem>0 && threadIdx.x==0){
      int cgt=gcnt[il*2];
      int ceq=min(gcnt[il*2+1],2048);
      int* eq=eqbuf+il*2048;
      for(int r2=0;r2<krem;r2++){
        int mn=0x7fffffff,mi=0;
        for(int j=0;j<ceq;j++) if(eq[j]<mn){mn=eq[j];mi=j;}
        s[cgt+r2]=mn; eq[mi]=0x7fffffff;
      }
    }
    __syncthreads();
  }
  for(int i=threadIdx.x;i<k;i+=256){
    int idx=s[i];
    skey[i]=((unsigned long long)fkey(o[idx])<<32)|(unsigned)(~(unsigned)idx);
  }
  __syncthreads();
  for(int i=threadIdx.x;i<k;i+=256){
    unsigned long long mk=skey[i];
    int rank=0;
    for(int j=0;j<k;j++) rank+=(skey[j]>mk)?1:0;
    int idx=(int)(~(unsigned)(mk&0xFFFFFFFFu));
    s[rank]=idx+c_off[lvl];
  }
}

// ---------------- K2a: decode+clip+score, build global sort keys, image max ----
__global__ __launch_bounds__(256) void k_decode(const float* __restrict__ obj,
    const float* __restrict__ del, const float* __restrict__ anc,
    const int* __restrict__ sel, float* __restrict__ pbox, float* __restrict__ pscore,
    int* __restrict__ plvl, unsigned long long* __restrict__ gkey,
    float* __restrict__ gmax){
  const int img=blockIdx.x;
  __shared__ float smax[256];
  const float BCLIP=(float)4.135166556742356;  // log(1000/16)
  float lm=0.f;
  for(int pos=threadIdx.x;pos<KTOT;pos+=256){
    int lvl = pos<1000?0:pos<2000?1:pos<3000?2:pos<4000?3:4;
    int tdx = sel[img*KTOT+pos];
    float logit = obj[(size_t)img*TT+tdx];
    const float* a=anc+4*(size_t)tdx;
    const float* d=del+((size_t)img*TT+tdx)*4;
    float w=a[2]-a[0], h=a[3]-a[1];
    float cx=a[0]+0.5f*w, cy=a[1]+0.5f*h;
    float dw=fminf(d[2],BCLIP), dh=fminf(d[3],BCLIP);
    float pcx=d[0]*w+cx, pcy=d[1]*h+cy;
    float pw=expf(dw)*w, ph=expf(dh)*h;
    float x1=pcx-0.5f*pw, y1=pcy-0.5f*ph;
    float x2=pcx+0.5f*pw, y2=pcy+0.5f*ph;
    x1=fminf(fmaxf(x1,0.f),800.f); y1=fminf(fmaxf(y1,0.f),800.f);
    x2=fminf(fmaxf(x2,0.f),800.f); y2=fminf(fmaxf(y2,0.f),800.f);
    int valid=(x2-x1>=1e-3f)&&(y2-y1>=1e-3f);
    float sc=1.f/(1.f+expf(-logit));
    float sv=valid? sc : -INFINITY;
    gkey[img*KTOT+pos]=((unsigned long long)fkey(sv)<<32)|(unsigned)(KTOT-1-pos);
    float* pb=pbox+((size_t)img*KTOT+pos)*4;
    pb[0]=x1; pb[1]=y1; pb[2]=x2; pb[3]=y2;
    pscore[img*KTOT+pos]=sc;
    plvl[img*KTOT+pos]=lvl|(valid?0:256);
    lm=fmaxf(lm,fmaxf(fmaxf(x1,y1),fmaxf(x2,y2)));
  }
  smax[threadIdx.x]=lm; __syncthreads();
  for(int st=128;st>0;st>>=1){
    if(threadIdx.x<st) smax[threadIdx.x]=fmaxf(smax[threadIdx.x],smax[threadIdx.x+st]);
    __syncthreads();
  }
  if(threadIdx.x==0) gmax[img]=smax[0];
}

// ---------------- K2b: partial rank counts, 256x256 tiles ---------------------
__global__ __launch_bounds__(256) void k_rankp(const unsigned long long* __restrict__ gkey,
    int* __restrict__ grank){
  const int img=blockIdx.x, ic=blockIdx.y, jc=blockIdx.z;
  __shared__ unsigned long long sk[256];
  const int jbase=jc*256;
  const int jend=min(256, KTOT-jbase);
  const int i=ic*256+threadIdx.x;
  if(threadIdx.x<jend) sk[threadIdx.x]=gkey[img*KTOT+jbase+threadIdx.x];
  __syncthreads();
  if(i>=KTOT) return;
  const unsigned long long mk=gkey[img*KTOT+i];
  int r=0;
  #pragma unroll 4
  for(int j=0;j<jend;j++) r+=(sk[j]>mk)?1:0;
  if(r) atomicAdd(&grank[img*KTOT+i], r);
}

// ---------------- K2c: scatter by rank ---------------------------------------
__global__ __launch_bounds__(256) void k_scatter(const int* __restrict__ grank,
    const float4* __restrict__ pbox, const float* __restrict__ pscore,
    const int* __restrict__ plvl,
    float4* __restrict__ sbox, float* __restrict__ sscore,
    int* __restrict__ slvl, int* __restrict__ ssupp){
  const int img=blockIdx.x/18, chunk=blockIdx.x%18;
  const int pos=chunk*256+threadIdx.x;
  if(pos>=KTOT) return;
  const int rank=grank[img*KTOT+pos];
  sbox[(size_t)img*KTOT+rank]=pbox[(size_t)img*KTOT+pos];
  sscore[img*KTOT+rank]=pscore[img*KTOT+pos];
  int lv=plvl[img*KTOT+pos];
  slvl[img*KTOT+rank]=lv&0xFF;
  ssupp[img*KTOT+rank]=(lv>>8)&1;   // invalid -> pre-suppressed
}

// ---------------- K3a: per-(img,level) ordered candidate list (wave ballot) ---
__global__ __launch_bounds__(64) void k_list(const float* __restrict__ sbox,
    const int* __restrict__ slvl, const int* __restrict__ ssupp,
    const float* __restrict__ gmax,
    int* __restrict__ lists, int* __restrict__ mcnt,
    float4* __restrict__ nbox, float* __restrict__ narea){
  const int img=blockIdx.x/5, lvl=blockIdx.x%5;
  const int lane=threadIdx.x;
  int* list = lists + blockIdx.x*1024;
  int base=0;
  for(int t=0;t<KTOT;t+=64){
    int r=t+lane;
    bool pred = (r<KTOT) && (slvl[img*KTOT+r]==lvl) && (ssupp[img*KTOT+r]==0);
    unsigned long long b=__ballot(pred);
    int prefix=__popcll(b & ((1ull<<lane)-1ull));
    if(pred) list[base+prefix]=r;
    base+=__popcll(b);
  }
  if(lane==0) mcnt[blockIdx.x]=base;
  const int m=base;
  const float off=(float)lvl*(gmax[img]+1.0f);   // replicate ref offset math exactly
  for(int i=lane;i<m;i+=64){
    int r=list[i];
    const float* bx=sbox+((size_t)img*KTOT+r)*4;
    float a0=bx[0]+off, a1=bx[1]+off, a2=bx[2]+off, a3=bx[3]+off;
    nbox[blockIdx.x*1024+i]=make_float4(a0,a1,a2,a3);
    narea[blockIdx.x*1024+i]=(a2-a0)*(a3-a1);
  }
}

// ---------------- K3b: pairwise suppression bitmasks, 1 word/thread ------------
__global__ __launch_bounds__(256) void k_mask(const float4* __restrict__ nbox,
    const float* __restrict__ narea, const int* __restrict__ mcnt,
    unsigned long long* __restrict__ mask){
  const int il=blockIdx.x;
  const int rc=blockIdx.y>>4, w=blockIdx.y&15;
  const int m=mcnt[il];
  const int r0=rc*256;
  if(r0>=m) return;
  const int i=r0+threadIdx.x;
  const int wlast=(m+63)>>6;
  __shared__ float4 sb[64];
  __shared__ float  sa[64];
  unsigned long long bits=0ull;
  const bool block_active = (w>=rc*4) && (w<wlast);   // rc*4 == min wi in block
  if(block_active){
    const int jend=min(64, m-w*64);
    if(threadIdx.x<64 && threadIdx.x<jend){
      sb[threadIdx.x]=nbox[il*1024+w*64+threadIdx.x];
      sa[threadIdx.x]=narea[il*1024+w*64+threadIdx.x];
    }
    __syncthreads();
    const int wi=i>>6;
    if(i<m && w>=wi){
      const float4 bi=nbox[il*1024+i];
      const float  ai=narea[il*1024+i];
      for(int jj=0;jj<jend;++jj){
        const float4 bj=sb[jj];                 // LDS broadcast
        float ltx=fmaxf(bi.x,bj.x), lty=fmaxf(bi.y,bj.y);
        float rbx=fminf(bi.z,bj.z), rby=fminf(bi.w,bj.w);
        float wx=fmaxf(rbx-ltx,0.f), wy=fmaxf(rby-lty,0.f);
        float inter=wx*wy;
        float iou=inter/((ai+sa[jj])-inter);
        bits |= (iou>0.7f)? (1ull<<jj) : 0ull;
      }
      if(w==wi){ int b=i&63; bits &= ~((2ull<<b)-1ull); }  // keep only j>i
    }
  }
  if(i<m) mask[((size_t)il*1024+i)*16+w]=bits;
}

// ---------------- K3c: greedy reduce; LDS-staged masks, wave-0 serial walk ----
__global__ __launch_bounds__(256) void k_reduce(const unsigned long long* __restrict__ mask,
    const int* __restrict__ mcnt, const int* __restrict__ lists,
    int* __restrict__ ssupp){
  const int il=blockIdx.x, img=il/5;
  const int m=mcnt[il];
  __shared__ unsigned long long smask[1024*16];   // 128 KB slab
  // cooperative global->LDS copy of the whole mask slab (float4-wide)
  {
    const float4* g4=(const float4*)(mask + (size_t)il*1024*16);
    float4* l4=(float4*)smask;
    const int tot4=m*8;                           // m rows x 128B
    for(int i=threadIdx.x;i<tot4;i+=256) l4[i]=g4[i];
  }
  __syncthreads();
  if(threadIdx.x>=64) return;
  const int lane=threadIdx.x;
  const bool ld = lane<16;
  unsigned long long remv=0ull;
  unsigned long long c0,c1,c2,c3,c4,c5,c6,c7;
  unsigned long long n0,n1,n2,n3,n4,n5,n6,n7;
#define LD(r,b) ((ld && ((b)+(r))<m) ? smask[(unsigned)((b)+(r))*16+lane] : 0ull)
  c0=LD(0,0); c1=LD(1,0); c2=LD(2,0); c3=LD(3,0);
  c4=LD(4,0); c5=LD(5,0); c6=LD(6,0); c7=LD(7,0);
  for(int g=0;;++g){
    const int nb=(g+1)*8;
    n0=LD(0,nb); n1=LD(1,nb); n2=LD(2,nb); n3=LD(3,nb);
    n4=LD(4,nb); n5=LD(5,nb); n6=LD(6,nb); n7=LD(7,nb);
    const int base=g*8;
    const int w=base>>6;
    const int bb=base&63;
    unsigned t8=(unsigned)(remv>>bb);
    unsigned am=0u;
#define DEC(r,cr) { unsigned alive=1u^((t8>>(r))&1u); am|=alive<<(r); \
                    if(alive) t8|=(unsigned)((cr)>>bb); }
    DEC(0,c0) DEC(1,c1) DEC(2,c2) DEC(3,c3)
    DEC(4,c4) DEC(5,c5) DEC(6,c6) DEC(7,c7)
#undef DEC
    const int rem=m-base;
    unsigned vm=(rem>=8)?0xffu:((rem<=0)?0u:((1u<<rem)-1u));
    am&=vm;
    unsigned am_w=(unsigned)__shfl((int)am, w);
    if(am_w&1u)   remv|=c0;
    if(am_w&2u)   remv|=c1;
    if(am_w&4u)   remv|=c2;
    if(am_w&8u)   remv|=c3;
    if(am_w&16u)  remv|=c4;
    if(am_w&32u)  remv|=c5;
    if(am_w&64u)  remv|=c6;
    if(am_w&128u) remv|=c7;
    if(nb>=m) break;
    c0=n0; c1=n1; c2=n2; c3=n3; c4=n4; c5=n5; c6=n6; c7=n7;
  }
#undef LD
  const int* list = lists + il*1024;
  for(int t=0;t<m;t+=64){
    int i=t+lane;
    unsigned long long word=__shfl(remv, (i<m? i:0)>>6);
    if(i<m && ((word>>(i&63))&1ull)) ssupp[img*KTOT+list[i]]=1;
  }
}

// ---------------- K4: compact first 1000 survivors per image ------------------
__global__ __launch_bounds__(256) void k_out(const float* __restrict__ sbox,
    const float* __restrict__ sscore, const int* __restrict__ ssupp,
    float* __restrict__ out){
  const int img=blockIdx.x;
  __shared__ unsigned short list[POST];
  __shared__ int s_c;
  if(threadIdx.x<64){
    int base=0;
    for(int t=0;t<KTOT && base<POST;t+=64){
      int r=t+threadIdx.x;
      bool pred = (r<KTOT) && (ssupp[img*KTOT+r]==0);
      unsigned long long b=__ballot(pred);
      int pre=__popcll(b & ((1ull<<threadIdx.x)-1ull));
      if(pred && base+pre<POST) list[base+pre]=(unsigned short)r;
      base+=__popcll(b);
    }
    if(threadIdx.x==0) s_c=min(base,POST);
  }
  __syncthreads();
  const int c=s_c;
  for(int o=threadIdx.x;o<POST;o+=256){
    float* row=out+((size_t)img*POST+o)*5;
    if(o<c){
      int r=list[o];
      const float* b=sbox+((size_t)img*KTOT+r)*4;
      row[0]=b[0]; row[1]=b[1]; row[2]=b[2]; row[3]=b[3];
      row[4]=sscore[img*KTOT+r];
    } else {
      row[0]=0.f; row[1]=0.f; row[2]=0.f; row[3]=0.f; row[4]=0.f;
    }
  }
}

extern "C" void kernel_launch(void* const* d_in, const int* in_sizes, int n_in,
                              void* d_out, int out_size, void* d_ws, size_t ws_size,
                              hipStream_t stream){
  const float* obj=(const float*)d_in[0];
  const float* del=(const float*)d_in[1];
  const float* anc=(const float*)d_in[2];
  float* out=(float*)d_out;

  char* w=(char*)d_ws;
  size_t off=0;
  auto alloc=[&](size_t bytes)->void*{
    void* p=w+off; off+=(bytes+255)&~(size_t)255; return p;
  };
  int*  sel    =(int*)  alloc(sizeof(int)*NIMG*KTOT);
  float* pbox  =(float*)alloc(sizeof(float)*NIMG*KTOT*4);
  float* pscore=(float*)alloc(sizeof(float)*NIMG*KTOT);
  int*  plvl   =(int*)  alloc(sizeof(int)*NIMG*KTOT);
  unsigned long long* gkey=(unsigned long long*)alloc(sizeof(unsigned long long)*NIMG*KTOT);
  float* sbox  =(float*)alloc(sizeof(float)*NIMG*KTOT*4);
  float* sscore=(float*)alloc(sizeof(float)*NIMG*KTOT);
  int*  slvl   =(int*)  alloc(sizeof(int)*NIMG*KTOT);
  int*  ssupp  =(int*)  alloc(sizeof(int)*NIMG*KTOT);
  float* gmax  =(float*)alloc(sizeof(float)*NIMG);
  int*  eqbuf  =(int*)  alloc(sizeof(int)*40*2048);
  int*  lists  =(int*)  alloc(sizeof(int)*40*1024);
  int*  mcnt   =(int*)  alloc(sizeof(int)*40);
  float4* nbox =(float4*)alloc(sizeof(float4)*40*1024);
  float* narea =(float*)alloc(sizeof(float)*40*1024);
  unsigned long long* mask=(unsigned long long*)alloc(sizeof(unsigned long long)*40*1024*16);
  unsigned* ghist=(unsigned*)alloc(sizeof(unsigned)*40*2048);
  unsigned* gpref=(unsigned*)alloc(sizeof(unsigned)*40);
  int*  gkrem  =(int*)  alloc(sizeof(int)*40);
  int*  gcnt   =(int*)  alloc(sizeof(int)*80);
  int*  grank  =(int*)  alloc(sizeof(int)*NIMG*KTOT);

  hipLaunchKernelGGL(k_zero,    dim3((40*2048+NIMG*KTOT+255)/256), dim3(256), 0, stream,
                     ghist, grank);
  hipLaunchKernelGGL(k_hist<0>, dim3(40,NSUB), dim3(256), 0, stream, obj, gpref, ghist);
  hipLaunchKernelGGL(k_scan<0>, dim3(40), dim3(256), 0, stream, ghist, gpref, gkrem, gcnt);
  hipLaunchKernelGGL(k_hist<1>, dim3(40,NSUB), dim3(256), 0, stream, obj, gpref, ghist);
  hipLaunchKernelGGL(k_scan<1>, dim3(40), dim3(256), 0, stream, ghist, gpref, gkrem, gcnt);
  hipLaunchKernelGGL(k_hist<2>, dim3(40,NSUB), dim3(256), 0, stream, obj, gpref, ghist);
  hipLaunchKernelGGL(k_scan<2>, dim3(40), dim3(256), 0, stream, ghist, gpref, gkrem, gcnt);
  hipLaunchKernelGGL(k_sel,    dim3(40,NSUB), dim3(256), 0, stream, obj, gpref, gkrem,
                     gcnt, sel, eqbuf);
  hipLaunchKernelGGL(k_sort,   dim3(40), dim3(256), 0, stream, obj, gkrem, gcnt, sel, eqbuf);
  hipLaunchKernelGGL(k_decode, dim3(NIMG), dim3(256), 0, stream, obj, del, anc, sel,
                     pbox, pscore, plvl, gkey, gmax);
  hipLaunchKernelGGL(k_rankp,  dim3(NIMG,18,18), dim3(256), 0, stream, gkey, grank);
  hipLaunchKernelGGL(k_scatter,dim3(NIMG*18), dim3(256), 0, stream, grank,
                     (const float4*)pbox, pscore, plvl,
                     (float4*)sbox, sscore, slvl, ssupp);
  hipLaunchKernelGGL(k_list,   dim3(40), dim3(64), 0, stream, sbox, slvl, ssupp, gmax,
                     lists, mcnt, nbox, narea);
  hipLaunchKernelGGL(k_mask,   dim3(40,64), dim3(256), 0, stream, nbox, narea, mcnt, mask);
  hipLaunchKernelGGL(k_reduce, dim3(40), dim3(256), 0, stream, mask, mcnt, lists, ssupp);
  hipLaunchKernelGGL(k_out,    dim3(NIMG), dim3(256), 0, stream, sbox, sscore, ssupp, out);
}

// Round 8
// 285.079 us; speedup vs baseline: 5.4136x; 1.1197x over previous
//
#include <hip/hip_runtime.h>
#include <math.h>

#define NIMG 8
#define TT   159882
#define KTOT 4507
#define POST 1000
#define NSUB 32

__constant__ int c_n[5]   = {120000,30000,7500,1875,507};
__constant__ int c_off[5] = {0,120000,150000,157500,159375};
__constant__ int c_k[5]   = {1000,1000,1000,1000,507};
__constant__ int c_pos[5] = {0,1000,2000,3000,4000};

__device__ __forceinline__ unsigned fkey(float f){
  unsigned u=__float_as_uint(f);
  return (u&0x80000000u)? ~u : (u|0x80000000u);
}

// ---------------- K0: zero global histograms + rank array ---------------------
__global__ __launch_bounds__(256) void k_zero(unsigned* __restrict__ ghist,
                                              int* __restrict__ grank){
  int i=blockIdx.x*256+threadIdx.x;
  if(i<40*2048) ghist[i]=0u;
  int j=i-40*2048;
  if(j>=0 && j<NIMG*KTOT) grank[j]=0;
}

// ---------------- K1a: distributed radix histogram (one round) ----------------
template<int RND>
__global__ __launch_bounds__(256) void k_hist(const float* __restrict__ obj,
    const unsigned* __restrict__ gpref, unsigned* __restrict__ ghist){
  constexpr int sh=(RND==0)?21:(RND==1)?10:0;
  constexpr int nb=(RND==2)?1024:2048;
  constexpr unsigned msk=(unsigned)(nb-1);
  const int il=blockIdx.x, sub=blockIdx.y;
  const int img=il/5, lvl=il%5;
  const int n=c_n[lvl], k=c_k[lvl];
  if(k>=n) return;
  const int chunk=(n+NSUB-1)/NSUB;
  const int start=sub*chunk, end=min(start+chunk,n);
  if(start>=end) return;
  const float* o=obj+(size_t)img*TT+c_off[lvl];
  __shared__ unsigned hist[2048];
  const unsigned prefix=(RND==0)?0u:gpref[il];
  for(int i=threadIdx.x;i<nb;i+=256) hist[i]=0u;
  __syncthreads();
  for(int i=start+threadIdx.x;i<end;i+=256){
    unsigned key=fkey(o[i]);
    if(RND==0){
      atomicAdd(&hist[(key>>sh)&msk],1u);
    } else {
      constexpr unsigned hiMask=0xFFFFFFFFu<<((RND==1)?21:10);
      if((key&hiMask)==prefix) atomicAdd(&hist[(key>>sh)&msk],1u);
    }
  }
  __syncthreads();
  for(int b=threadIdx.x;b<nb;b+=256){
    unsigned v=hist[b];
    if(v) atomicAdd(&ghist[il*2048+b],v);
  }
}

// ---------------- K1b: pick bucket via register suffix-sum + LDS tree ---------
template<int RND>
__global__ __launch_bounds__(256) void k_scan(unsigned* __restrict__ ghist,
    unsigned* __restrict__ gpref, int* __restrict__ gkrem,
    int* __restrict__ gcnt){
  constexpr int sh=(RND==0)?21:(RND==1)?10:0;
  constexpr int nb=(RND==2)?1024:2048;
  constexpr int C=nb/256;
  const int il=blockIdx.x, lvl=il%5;
  const int n=c_n[lvl], k=c_k[lvl];
  const int t=threadIdx.x;
  __shared__ unsigned tot[256];
  if(k>=n){
    if(RND==2 && t==0){ gpref[il]=0u; gkrem[il]=0; gcnt[il*2]=0; gcnt[il*2+1]=0; }
    return;
  }
  const int kr=(RND==0)?k:gkrem[il];
  unsigned v[C];
#pragma unroll
  for(int i=0;i<C;i++) v[i]=ghist[il*2048+t*C+i];
#pragma unroll
  for(int i=C-2;i>=0;i--) v[i]+=v[i+1];          // local suffix sum (registers)
  tot[t]=v[0];
  __syncthreads();
#pragma unroll
  for(int d=1;d<256;d<<=1){                       // inclusive suffix scan of totals
    unsigned add=(t+d<256)?tot[t+d]:0u;
    __syncthreads();
    tot[t]+=add;
    __syncthreads();
  }
  unsigned tail=(t<255)?tot[t+1]:0u;
#pragma unroll
  for(int i=0;i<C;i++){
    unsigned suf=v[i]+tail;
    unsigned sufn=((i<C-1)?v[i+1]:0u)+tail;
    if(suf>=(unsigned)kr && sufn<(unsigned)kr){
      unsigned prevPref=(RND==0)?0u:gpref[il];
      gpref[il]=prevPref|((unsigned)(t*C+i)<<sh);
      gkrem[il]=kr-(int)sufn;
    }
  }
  for(int b=t;b<2048;b+=256) ghist[il*2048+b]=0u; // ready for next round/replay
  if(RND==2 && t==0){ gcnt[il*2]=0; gcnt[il*2+1]=0; }
}

// ---------------- K1c: distributed selection against final threshold ---------
__global__ __launch_bounds__(256) void k_sel(const float* __restrict__ obj,
    const unsigned* __restrict__ gpref, const int* __restrict__ gkrem,
    int* __restrict__ gcnt, int* __restrict__ sel, int* __restrict__ eqbuf){
  const int il=blockIdx.x, sub=blockIdx.y;
  const int img=il/5, lvl=il%5;
  const int n=c_n[lvl], k=c_k[lvl];
  const int chunk=(n+NSUB-1)/NSUB;
  const int start=sub*chunk, end=min(start+chunk,n);
  if(start>=end) return;
  int* s=sel+img*KTOT+c_pos[lvl];
  if(k>=n){
    for(int i=start+threadIdx.x;i<end;i+=256) s[i]=i;
    return;
  }
  const float* o=obj+(size_t)img*TT+c_off[lvl];
  const unsigned t=gpref[il];
  const int krem=gkrem[il];
  for(int i=start+threadIdx.x;i<end;i+=256){
    unsigned key=fkey(o[i]);
    if(key>t){ s[atomicAdd(&gcnt[il*2],1)]=i; }
    else if(key==t && krem>0){ int p=atomicAdd(&gcnt[il*2+1],1); if(p<2048) eqbuf[il*2048+p]=i; }
  }
}

// ---------------- K1d: eq-tiebreak picks + level rank sort --------------------
__global__ __launch_bounds__(256) void k_sort(const float* __restrict__ obj,
    const int* __restrict__ gkrem, const int* __restrict__ gcnt,
    int* __restrict__ sel, int* __restrict__ eqbuf){
  const int il=blockIdx.x, img=il/5, lvl=il%5;
  const int n=c_n[lvl], k=c_k[lvl];
  const float* o=obj+(size_t)img*TT+c_off[lvl];
  int* s=sel+img*KTOT+c_pos[lvl];
  __shared__ unsigned long long skey[1024];
  if(k<n){
    const int krem=gkrem[il];
    if(krem>0 && threadIdx.x==0){
      int cgt=gcnt[il*2];
      int ceq=min(gcnt[il*2+1],2048);
      int* eq=eqbuf+il*2048;
      for(int r2=0;r2<krem;r2++){
        int mn=0x7fffffff,mi=0;
        for(int j=0;j<ceq;j++) if(eq[j]<mn){mn=eq[j];mi=j;}
        s[cgt+r2]=mn; eq[mi]=0x7fffffff;
      }
    }
    __syncthreads();
  }
  for(int i=threadIdx.x;i<k;i+=256){
    int idx=s[i];
    skey[i]=((unsigned long long)fkey(o[idx])<<32)|(unsigned)(~(unsigned)idx);
  }
  __syncthreads();
  for(int i=threadIdx.x;i<k;i+=256){
    unsigned long long mk=skey[i];
    int rank=0;
    for(int j=0;j<k;j++) rank+=(skey[j]>mk)?1:0;
    int idx=(int)(~(unsigned)(mk&0xFFFFFFFFu));
    s[rank]=idx+c_off[lvl];
  }
}

// ---------------- K2a: decode+clip+score, build global sort keys, image max ----
__global__ __launch_bounds__(256) void k_decode(const float* __restrict__ obj,
    const float* __restrict__ del, const float* __restrict__ anc,
    const int* __restrict__ sel, float* __restrict__ pbox, float* __restrict__ pscore,
    int* __restrict__ plvl, unsigned long long* __restrict__ gkey,
    float* __restrict__ gmax){
  const int img=blockIdx.x;
  __shared__ float smax[256];
  const float BCLIP=(float)4.135166556742356;  // log(1000/16)
  float lm=0.f;
  for(int pos=threadIdx.x;pos<KTOT;pos+=256){
    int lvl = pos<1000?0:pos<2000?1:pos<3000?2:pos<4000?3:4;
    int tdx = sel[img*KTOT+pos];
    float logit = obj[(size_t)img*TT+tdx];
    const float* a=anc+4*(size_t)tdx;
    const float* d=del+((size_t)img*TT+tdx)*4;
    float w=a[2]-a[0], h=a[3]-a[1];
    float cx=a[0]+0.5f*w, cy=a[1]+0.5f*h;
    float dw=fminf(d[2],BCLIP), dh=fminf(d[3],BCLIP);
    float pcx=d[0]*w+cx, pcy=d[1]*h+cy;
    float pw=expf(dw)*w, ph=expf(dh)*h;
    float x1=pcx-0.5f*pw, y1=pcy-0.5f*ph;
    float x2=pcx+0.5f*pw, y2=pcy+0.5f*ph;
    x1=fminf(fmaxf(x1,0.f),800.f); y1=fminf(fmaxf(y1,0.f),800.f);
    x2=fminf(fmaxf(x2,0.f),800.f); y2=fminf(fmaxf(y2,0.f),800.f);
    int valid=(x2-x1>=1e-3f)&&(y2-y1>=1e-3f);
    float sc=1.f/(1.f+expf(-logit));
    float sv=valid? sc : -INFINITY;
    gkey[img*KTOT+pos]=((unsigned long long)fkey(sv)<<32)|(unsigned)(KTOT-1-pos);
    float* pb=pbox+((size_t)img*KTOT+pos)*4;
    pb[0]=x1; pb[1]=y1; pb[2]=x2; pb[3]=y2;
    pscore[img*KTOT+pos]=sc;
    plvl[img*KTOT+pos]=lvl|(valid?0:256);
    lm=fmaxf(lm,fmaxf(fmaxf(x1,y1),fmaxf(x2,y2)));
  }
  smax[threadIdx.x]=lm; __syncthreads();
  for(int st=128;st>0;st>>=1){
    if(threadIdx.x<st) smax[threadIdx.x]=fmaxf(smax[threadIdx.x],smax[threadIdx.x+st]);
    __syncthreads();
  }
  if(threadIdx.x==0) gmax[img]=smax[0];
}

// ---------------- K2b: partial rank counts, 256x256 tiles ---------------------
__global__ __launch_bounds__(256) void k_rankp(const unsigned long long* __restrict__ gkey,
    int* __restrict__ grank){
  const int img=blockIdx.x, ic=blockIdx.y, jc=blockIdx.z;
  __shared__ unsigned long long sk[256];
  const int jbase=jc*256;
  const int jend=min(256, KTOT-jbase);
  const int i=ic*256+threadIdx.x;
  if(threadIdx.x<jend) sk[threadIdx.x]=gkey[img*KTOT+jbase+threadIdx.x];
  __syncthreads();
  if(i>=KTOT) return;
  const unsigned long long mk=gkey[img*KTOT+i];
  int r=0;
  #pragma unroll 4
  for(int j=0;j<jend;j++) r+=(sk[j]>mk)?1:0;
  if(r) atomicAdd(&grank[img*KTOT+i], r);
}

// ---------------- K2c: scatter by rank ---------------------------------------
__global__ __launch_bounds__(256) void k_scatter(const int* __restrict__ grank,
    const float4* __restrict__ pbox, const float* __restrict__ pscore,
    const int* __restrict__ plvl,
    float4* __restrict__ sbox, float* __restrict__ sscore,
    int* __restrict__ slvl, int* __restrict__ ssupp){
  const int img=blockIdx.x/18, chunk=blockIdx.x%18;
  const int pos=chunk*256+threadIdx.x;
  if(pos>=KTOT) return;
  const int rank=grank[img*KTOT+pos];
  sbox[(size_t)img*KTOT+rank]=pbox[(size_t)img*KTOT+pos];
  sscore[img*KTOT+rank]=pscore[img*KTOT+pos];
  int lv=plvl[img*KTOT+pos];
  slvl[img*KTOT+rank]=lv&0xFF;
  ssupp[img*KTOT+rank]=(lv>>8)&1;   // invalid -> pre-suppressed
}

// ---------------- K3a: candidate list; LDS-staged predicate, wave-0 ballot ----
__global__ __launch_bounds__(256) void k_list(const float* __restrict__ sbox,
    const int* __restrict__ slvl, const int* __restrict__ ssupp,
    const float* __restrict__ gmax,
    int* __restrict__ lists, int* __restrict__ mcnt,
    float4* __restrict__ nbox, float* __restrict__ narea){
  const int img=blockIdx.x/5, lvl=blockIdx.x%5;
  const int tid=threadIdx.x;
  __shared__ unsigned char s_ok[KTOT];
  __shared__ int s_list[1024];
  __shared__ int s_m;
  for(int i=tid;i<KTOT;i+=256)
    s_ok[i]=(slvl[img*KTOT+i]==lvl && ssupp[img*KTOT+i]==0)?1:0;
  __syncthreads();
  if(tid<64){
    int base=0;
    for(int t=0;t<KTOT;t+=64){
      int r=t+tid;
      bool pred=(r<KTOT) && s_ok[r];
      unsigned long long b=__ballot(pred);
      int pre=__popcll(b & ((1ull<<tid)-1ull));
      if(pred) s_list[base+pre]=r;
      base+=__popcll(b);
    }
    if(tid==0){ s_m=base; mcnt[blockIdx.x]=base; }
  }
  __syncthreads();
  const int m=s_m;
  const float off=(float)lvl*(gmax[img]+1.0f);   // replicate ref offset math exactly
  const float4* sb4=(const float4*)sbox;
  for(int i=tid;i<m;i+=256){
    int r=s_list[i];
    lists[blockIdx.x*1024+i]=r;
    float4 bx=sb4[(size_t)img*KTOT+r];
    float a0=bx.x+off, a1=bx.y+off, a2=bx.z+off, a3=bx.w+off;
    nbox[blockIdx.x*1024+i]=make_float4(a0,a1,a2,a3);
    narea[blockIdx.x*1024+i]=(a2-a0)*(a3-a1);
  }
}

// ---------------- K3b: pairwise suppression bitmasks, 1 word/thread ------------
__global__ __launch_bounds__(256) void k_mask(const float4* __restrict__ nbox,
    const float* __restrict__ narea, const int* __restrict__ mcnt,
    unsigned long long* __restrict__ mask){
  const int il=blockIdx.x;
  const int rc=blockIdx.y>>4, w=blockIdx.y&15;
  const int m=mcnt[il];
  const int r0=rc*256;
  if(r0>=m) return;
  const int i=r0+threadIdx.x;
  const int wlast=(m+63)>>6;
  __shared__ float4 sb[64];
  __shared__ float  sa[64];
  unsigned long long bits=0ull;
  const bool block_active = (w>=rc*4) && (w<wlast);   // rc*4 == min wi in block
  if(block_active){
    const int jend=min(64, m-w*64);
    if(threadIdx.x<64 && threadIdx.x<jend){
      sb[threadIdx.x]=nbox[il*1024+w*64+threadIdx.x];
      sa[threadIdx.x]=narea[il*1024+w*64+threadIdx.x];
    }
    __syncthreads();
    const int wi=i>>6;
    if(i<m && w>=wi){
      const float4 bi=nbox[il*1024+i];
      const float  ai=narea[il*1024+i];
      for(int jj=0;jj<jend;++jj){
        const float4 bj=sb[jj];                 // LDS broadcast
        float ltx=fmaxf(bi.x,bj.x), lty=fmaxf(bi.y,bj.y);
        float rbx=fminf(bi.z,bj.z), rby=fminf(bi.w,bj.w);
        float wx=fmaxf(rbx-ltx,0.f), wy=fmaxf(rby-lty,0.f);
        float inter=wx*wy;
        float iou=inter/((ai+sa[jj])-inter);
        bits |= (iou>0.7f)? (1ull<<jj) : 0ull;
      }
      if(w==wi){ int b=i&63; bits &= ~((2ull<<b)-1ull); }  // keep only j>i
    }
  }
  if(i<m) mask[((size_t)il*1024+i)*16+w]=bits;
}

// ---------------- K3c: greedy reduce; batched LDS stage + readlane walk -------
__global__ __launch_bounds__(256) void k_reduce(const unsigned long long* __restrict__ mask,
    const int* __restrict__ mcnt, const int* __restrict__ lists,
    int* __restrict__ ssupp){
  const int il=blockIdx.x, img=il/5;
  const int m=mcnt[il];
  __shared__ unsigned long long smask[1024*16];   // 128 KB slab
  // cooperative global->LDS copy, 8 loads in flight per thread, no tail loop
  {
    const float4* g4=(const float4*)(mask + (size_t)il*1024*16);
    float4* l4=(float4*)smask;
    const int tot4=(m*8+2047)&~2047;              // <= 8192 always (m<=1000)
    for(int i=threadIdx.x;i<tot4;i+=2048){
      float4 r0=g4[i      ], r1=g4[i+ 256], r2=g4[i+ 512], r3=g4[i+ 768];
      float4 r4=g4[i+1024], r5=g4[i+1280], r6=g4[i+1536], r7=g4[i+1792];
      l4[i      ]=r0; l4[i+ 256]=r1; l4[i+ 512]=r2; l4[i+ 768]=r3;
      l4[i+1024]=r4; l4[i+1280]=r5; l4[i+1536]=r6; l4[i+1792]=r7;
    }
  }
  __syncthreads();
  if(threadIdx.x>=64) return;
  const int lane=threadIdx.x;
  const bool ld = lane<16;
  unsigned long long remv=0ull;
  unsigned long long c0,c1,c2,c3,c4,c5,c6,c7;
  unsigned long long n0,n1,n2,n3,n4,n5,n6,n7;
#define LD(r,b) ((ld && ((b)+(r))<m) ? smask[(unsigned)((b)+(r))*16+lane] : 0ull)
  c0=LD(0,0); c1=LD(1,0); c2=LD(2,0); c3=LD(3,0);
  c4=LD(4,0); c5=LD(5,0); c6=LD(6,0); c7=LD(7,0);
  for(int g=0;;++g){
    const int nb=(g+1)*8;
    n0=LD(0,nb); n1=LD(1,nb); n2=LD(2,nb); n3=LD(3,nb);
    n4=LD(4,nb); n5=LD(5,nb); n6=LD(6,nb); n7=LD(7,nb);
    const int base=g*8;
    const int w=base>>6;          // wave-uniform
    const int bb=base&63;
    unsigned t8=(unsigned)(remv>>bb);
    unsigned am=0u;
#define DEC(r,cr) { unsigned alive=1u^((t8>>(r))&1u); am|=alive<<(r); \
                    if(alive) t8|=(unsigned)((cr)>>bb); }
    DEC(0,c0) DEC(1,c1) DEC(2,c2) DEC(3,c3)
    DEC(4,c4) DEC(5,c5) DEC(6,c6) DEC(7,c7)
#undef DEC
    const int rem=m-base;
    unsigned vm=(rem>=8)?0xffu:((rem<=0)?0u:((1u<<rem)-1u));
    am&=vm;
    unsigned am_w=__builtin_amdgcn_readlane(am, w);   // SALU path, no LDS op
    if(am_w&1u)   remv|=c0;
    if(am_w&2u)   remv|=c1;
    if(am_w&4u)   remv|=c2;
    if(am_w&8u)   remv|=c3;
    if(am_w&16u)  remv|=c4;
    if(am_w&32u)  remv|=c5;
    if(am_w&64u)  remv|=c6;
    if(am_w&128u) remv|=c7;
    if(nb>=m) break;
    c0=n0; c1=n1; c2=n2; c3=n3; c4=n4; c5=n5; c6=n6; c7=n7;
  }
#undef LD
  const int* list = lists + il*1024;
  for(int t=0;t<m;t+=64){
    int i=t+lane;
    unsigned long long word=__shfl(remv, (i<m? i:0)>>6);
    if(i<m && ((word>>(i&63))&1ull)) ssupp[img*KTOT+list[i]]=1;
  }
}

// ---------------- K4: compact survivors; LDS-staged predicate -----------------
__global__ __launch_bounds__(256) void k_out(const float* __restrict__ sbox,
    const float* __restrict__ sscore, const int* __restrict__ ssupp,
    float* __restrict__ out){
  const int img=blockIdx.x;
  const int tid=threadIdx.x;
  __shared__ unsigned char s_ok[KTOT];
  __shared__ unsigned short list[POST];
  __shared__ int s_c;
  for(int i=tid;i<KTOT;i+=256) s_ok[i]=(ssupp[img*KTOT+i]==0)?1:0;
  __syncthreads();
  if(tid<64){
    int base=0;
    for(int t=0;t<KTOT && base<POST;t+=64){
      int r=t+tid;
      bool pred=(r<KTOT) && s_ok[r];
      unsigned long long b=__ballot(pred);
      int pre=__popcll(b & ((1ull<<tid)-1ull));
      if(pred && base+pre<POST) list[base+pre]=(unsigned short)r;
      base+=__popcll(b);
    }
    if(tid==0) s_c=min(base,POST);
  }
  __syncthreads();
  const int c=s_c;
  for(int o=tid;o<POST;o+=256){
    float* row=out+((size_t)img*POST+o)*5;
    if(o<c){
      int r=list[o];
      const float* b=sbox+((size_t)img*KTOT+r)*4;
      row[0]=b[0]; row[1]=b[1]; row[2]=b[2]; row[3]=b[3];
      row[4]=sscore[img*KTOT+r];
    } else {
      row[0]=0.f; row[1]=0.f; row[2]=0.f; row[3]=0.f; row[4]=0.f;
    }
  }
}

extern "C" void kernel_launch(void* const* d_in, const int* in_sizes, int n_in,
                              void* d_out, int out_size, void* d_ws, size_t ws_size,
                              hipStream_t stream){
  const float* obj=(const float*)d_in[0];
  const float* del=(const float*)d_in[1];
  const float* anc=(const float*)d_in[2];
  float* out=(float*)d_out;

  char* w=(char*)d_ws;
  size_t off=0;
  auto alloc=[&](size_t bytes)->void*{
    void* p=w+off; off+=(bytes+255)&~(size_t)255; return p;
  };
  int*  sel    =(int*)  alloc(sizeof(int)*NIMG*KTOT);
  float* pbox  =(float*)alloc(sizeof(float)*NIMG*KTOT*4);
  float* pscore=(float*)alloc(sizeof(float)*NIMG*KTOT);
  int*  plvl   =(int*)  alloc(sizeof(int)*NIMG*KTOT);
  unsigned long long* gkey=(unsigned long long*)alloc(sizeof(unsigned long long)*NIMG*KTOT);
  float* sbox  =(float*)alloc(sizeof(float)*NIMG*KTOT*4);
  float* sscore=(float*)alloc(sizeof(float)*NIMG*KTOT);
  int*  slvl   =(int*)  alloc(sizeof(int)*NIMG*KTOT);
  int*  ssupp  =(int*)  alloc(sizeof(int)*NIMG*KTOT);
  float* gmax  =(float*)alloc(sizeof(float)*NIMG);
  int*  eqbuf  =(int*)  alloc(sizeof(int)*40*2048);
  int*  lists  =(int*)  alloc(sizeof(int)*40*1024);
  int*  mcnt   =(int*)  alloc(sizeof(int)*40);
  float4* nbox =(float4*)alloc(sizeof(float4)*40*1024);
  float* narea =(float*)alloc(sizeof(float)*40*1024);
  unsigned long long* mask=(unsigned long long*)alloc(sizeof(unsigned long long)*40*1024*16);
  unsigned* ghist=(unsigned*)alloc(sizeof(unsigned)*40*2048);
  unsigned* gpref=(unsigned*)alloc(sizeof(unsigned)*40);
  int*  gkrem  =(int*)  alloc(sizeof(int)*40);
  int*  gcnt   =(int*)  alloc(sizeof(int)*80);
  int*  grank  =(int*)  alloc(sizeof(int)*NIMG*KTOT);

  hipLaunchKernelGGL(k_zero,    dim3((40*2048+NIMG*KTOT+255)/256), dim3(256), 0, stream,
                     ghist, grank);
  hipLaunchKernelGGL(k_hist<0>, dim3(40,NSUB), dim3(256), 0, stream, obj, gpref, ghist);
  hipLaunchKernelGGL(k_scan<0>, dim3(40), dim3(256), 0, stream, ghist, gpref, gkrem, gcnt);
  hipLaunchKernelGGL(k_hist<1>, dim3(40,NSUB), dim3(256), 0, stream, obj, gpref, ghist);
  hipLaunchKernelGGL(k_scan<1>, dim3(40), dim3(256), 0, stream, ghist, gpref, gkrem, gcnt);
  hipLaunchKernelGGL(k_hist<2>, dim3(40,NSUB), dim3(256), 0, stream, obj, gpref, ghist);
  hipLaunchKernelGGL(k_scan<2>, dim3(40), dim3(256), 0, stream, ghist, gpref, gkrem, gcnt);
  hipLaunchKernelGGL(k_sel,    dim3(40,NSUB), dim3(256), 0, stream, obj, gpref, gkrem,
                     gcnt, sel, eqbuf);
  hipLaunchKernelGGL(k_sort,   dim3(40), dim3(256), 0, stream, obj, gkrem, gcnt, sel, eqbuf);
  hipLaunchKernelGGL(k_decode, dim3(NIMG), dim3(256), 0, stream, obj, del, anc, sel,
                     pbox, pscore, plvl, gkey, gmax);
  hipLaunchKernelGGL(k_rankp,  dim3(NIMG,18,18), dim3(256), 0, stream, gkey, grank);
  hipLaunchKernelGGL(k_scatter,dim3(NIMG*18), dim3(256), 0, stream, grank,
                     (const float4*)pbox, pscore, plvl,
                     (float4*)sbox, sscore, slvl, ssupp);
  hipLaunchKernelGGL(k_list,   dim3(40), dim3(256), 0, stream, sbox, slvl, ssupp, gmax,
                     lists, mcnt, nbox, narea);
  hipLaunchKernelGGL(k_mask,   dim3(40,64), dim3(256), 0, stream, nbox, narea, mcnt, mask);
  hipLaunchKernelGGL(k_reduce, dim3(40), dim3(256), 0, stream, mask, mcnt, lists, ssupp);
  hipLaunchKernelGGL(k_out,    dim3(NIMG), dim3(256), 0, stream, sbox, sscore, ssupp, out);
}